// Round 12
// baseline (415.952 us; speedup 1.0000x reference)
//
#include <hip/hip_runtime.h>
#include <hip/hip_bf16.h>
#include <cstdint>
#include <cstddef>

constexpr int CB  = 8;
constexpr int CS  = 2048;
constexpr int CH  = 256;
constexpr int CNH = 4;
constexpr int CDH = 64;
constexpr int CT  = CB * CS;   // 16384 tokens

typedef __attribute__((ext_vector_type(8)))  __bf16 bf16x8;
typedef __attribute__((ext_vector_type(4)))  float  f32x4;
typedef __attribute__((ext_vector_type(16))) float  f32x16;
typedef __attribute__((ext_vector_type(2)))  int    i32x2;

__device__ __forceinline__ float b2f(unsigned short u) {
    union { float f; unsigned int i; } v; v.i = ((unsigned int)u) << 16; return v.f;
}
__device__ __forceinline__ unsigned short f2b(float f) {
    union { float f; unsigned int i; } v; v.f = f;
    unsigned int r = v.i + 0x7FFFu + ((v.i >> 16) & 1u);
    return (unsigned short)(r >> 16);
}
__device__ __forceinline__ unsigned short f2b_fast(float f) {  // round-half-up
    union { float f; unsigned int i; } v; v.f = f;
    return (unsigned short)((v.i + 0x8000u) >> 16);
}
__device__ __forceinline__ unsigned int packbf(float a, float b) {
    return (unsigned int)f2b_fast(a) | ((unsigned int)f2b_fast(b) << 16);
}
__device__ __forceinline__ float fexp2(float x) {
#if __has_builtin(__builtin_amdgcn_exp2f)
    return __builtin_amdgcn_exp2f(x);
#else
    float r; asm("v_exp_f32 %0, %1" : "=v"(r) : "v"(x)); return r;
#endif
}
__device__ __forceinline__ f32x4 mfma16(bf16x8 a, bf16x8 b, f32x4 c) {
    return __builtin_amdgcn_mfma_f32_16x16x32_bf16(a, b, c, 0, 0, 0);
}
__device__ __forceinline__ f32x16 mfma32(bf16x8 a, bf16x8 b, f32x16 c) {
    return __builtin_amdgcn_mfma_f32_32x32x16_bf16(a, b, c, 0, 0, 0);
}
__device__ __forceinline__ f32x16 zero16() {
    f32x16 z;
    #pragma unroll
    for (int i = 0; i < 16; ++i) z[i] = 0.f;
    return z;
}

#define GLOAD_LDS16(gptr, lptr)                                                        \
    __builtin_amdgcn_global_load_lds((const __attribute__((address_space(1))) void*)(gptr), \
                                     (__attribute__((address_space(3))) void*)(lptr), 16, 0, 0)

// log2(e)/sqrt(DH): folded into Q projection so softmax uses raw exp2
#define QSCALE 0.1803368801111204f

// ---------------- dtype detect: reading f32 data as bf16 yields huge/NaN values ----
__global__ __launch_bounds__(256) void detect_kernel(
    const unsigned short* __restrict__ h, int* __restrict__ flag)
{
    __shared__ int s_bad;
    const int tid = threadIdx.x;
    if (tid == 0) s_bad = 0;
    __syncthreads();
    bool bad = false;
    for (int i = tid; i < 2048; i += 256) {
        float v = b2f(h[i]);
        if (!(fabsf(v) < 1e25f)) bad = true;   // NaN also lands here
    }
    if (bad) s_bad = 1;
    __syncthreads();
    if (tid == 0) *flag = s_bad;               // 1 => buffers are f32, 0 => bf16
}

// ---------------- converters (runtime input dtype via flag) -----------------------
struct CvtW { const void* src[7]; void* dst[7]; int n[7]; };   // -> bf16 (weights+hidden)
struct CvtB { const void* src[10]; void* dst[10]; int n[10]; };// -> f32 (biases/ln, tiny)

__global__ __launch_bounds__(256) void cvt_wb_k(const int* __restrict__ flag, CvtW a)
{
    const int seg = blockIdx.y, n = a.n[seg];
    const bool inf32 = (*flag != 0);
    const float* sf = (const float*)a.src[seg];
    const unsigned short* sb = (const unsigned short*)a.src[seg];
    unsigned short* d = (unsigned short*)a.dst[seg];
    for (int i = (blockIdx.x * 256 + threadIdx.x) * 4; i < n; i += gridDim.x * 1024) {
        ushort4 o;
        if (inf32) {
            float4 v = *(const float4*)(sf + i);
            o.x = f2b(v.x); o.y = f2b(v.y); o.z = f2b(v.z); o.w = f2b(v.w);
        } else {
            o = *(const ushort4*)(sb + i);
        }
        *(ushort4*)(d + i) = o;
    }
}

__global__ __launch_bounds__(256) void cvt_bf_k(const int* __restrict__ flag, CvtB a)
{
    const int seg = blockIdx.y, n = a.n[seg];
    const bool inf32 = (*flag != 0);
    const float* sf = (const float*)a.src[seg];
    const unsigned short* sb = (const unsigned short*)a.src[seg];
    float* d = (float*)a.dst[seg];
    const int i = threadIdx.x * 4;
    if (i < n) {
        float4 o;
        if (inf32) {
            o = *(const float4*)(sf + i);
        } else {
            ushort4 v = *(const ushort4*)(sb + i);
            o.x = b2f(v.x); o.y = b2f(v.y); o.z = b2f(v.z); o.w = b2f(v.w);
        }
        *(float4*)(d + i) = o;
    }
}

// ---------------- LayerNorm: one wave per token (H=256, 4 elems/lane), bf16 in ----
__global__ __launch_bounds__(256) void ln_kernel(
    const unsigned short* __restrict__ x, const float* __restrict__ w,
    const float* __restrict__ b, unsigned short* __restrict__ out)
{
    const int wave = threadIdx.x >> 6, lane = threadIdx.x & 63;
    const int token = blockIdx.x * 4 + wave;
    const int c = lane * 4;
    const size_t rowo = (size_t)token * CH + c;
    ushort4 u = *(const ushort4*)(x + rowo);
    float v0 = b2f(u.x), v1 = b2f(u.y), v2 = b2f(u.z), v3 = b2f(u.w);
    float s = v0 + v1 + v2 + v3;
    float q = v0*v0 + v1*v1 + v2*v2 + v3*v3;
    #pragma unroll
    for (int m = 1; m < 64; m <<= 1) { s += __shfl_xor(s, m, 64); q += __shfl_xor(q, m, 64); }
    float mean = s * (1.0f/256.0f);
    float var  = q * (1.0f/256.0f) - mean*mean;
    float inv  = rsqrtf(var + 1e-12f);
    float4 ww = *(const float4*)(w + c);
    float4 bb = *(const float4*)(b + c);
    ushort4 o;
    o.x = f2b(ww.x * (v0-mean)*inv + bb.x);
    o.y = f2b(ww.y * (v1-mean)*inv + bb.y);
    o.z = f2b(ww.z * (v2-mean)*inv + bb.z);
    o.w = f2b(ww.w * (v3-mean)*inv + bb.w);
    *(ushort4*)(out + rowo) = o;
}

// ---------------- 128x128 bf16 MFMA GEMM (round-5 proven structure, BK=32) --------
// A:[M][K] W:[N][K] bf16; bias f32; resid bf16. 4 waves, each 64x64 (4x4 frags).
// storemode: 0=row, 1=head ([B][NH][S][DH]), 2=V^T ([B][NH][DH][S], 8B packed).
template<bool GELU, bool RESID, bool OUTDYN>
__device__ __forceinline__ void gemm_core(
    const unsigned short* __restrict__ A, const unsigned short* __restrict__ W,
    const float* __restrict__ bias, const unsigned short* __restrict__ resid,
    void* __restrict__ out, const int* __restrict__ flag,
    int K, int N, int m0, int n0, float oscale, int storemode)
{
    __shared__ __align__(16) unsigned short lA[128*32];
    __shared__ __align__(16) unsigned short lB[128*32];
    const int tid  = threadIdx.x;
    const int lane = tid & 63;
    const int wave = tid >> 6;
    const int wr = (wave >> 1) * 64;
    const int wc = (wave & 1) * 64;
    const int g = lane >> 4, r16 = lane & 15;
    const int lrow = lane >> 2;        // 0..15 rows within 1KB chunk
    const int lch  = lane & 3;         // 16B chunk within 64B row

    const f32x4 zero = {0.f, 0.f, 0.f, 0.f};
    f32x4 acc[4][4];
    #pragma unroll
    for (int m = 0; m < 4; ++m)
        #pragma unroll
        for (int n = 0; n < 4; ++n) acc[m][n] = zero;

    for (int k0 = 0; k0 < K; k0 += 32) {
        #pragma unroll
        for (int i = 0; i < 2; ++i) {
            int chunk = wave + i * 4;              // 0..7 (1KB chunks of 8KB tile)
            int row = chunk * 16 + lrow;           // tile row
            const unsigned short* ga = A + (size_t)(m0 + row) * K + k0 + lch * 8;
            GLOAD_LDS16(ga, &lA[chunk * 512]);
            const unsigned short* gw = W + (size_t)(n0 + row) * K + k0 + lch * 8;
            GLOAD_LDS16(gw, &lB[chunk * 512]);
        }
        __syncthreads();
        bf16x8 af[4], wf[4];
        #pragma unroll
        for (int m = 0; m < 4; ++m) af[m] = *(const bf16x8*)&lA[(wr + m*16 + r16) * 32 + g * 8];
        #pragma unroll
        for (int n = 0; n < 4; ++n) wf[n] = *(const bf16x8*)&lB[(wc + n*16 + r16) * 32 + g * 8];
        #pragma unroll
        for (int m = 0; m < 4; ++m)
            #pragma unroll
            for (int n = 0; n < 4; ++n)
                acc[m][n] = mfma16(af[m], wf[n], acc[m][n]);
        __syncthreads();
    }

    const bool of32dyn = OUTDYN ? (*flag != 0) : false;
    #pragma unroll
    for (int n = 0; n < 4; ++n) {
        int col = n0 + wc + n*16 + r16;
        float bv = bias[col];
        #pragma unroll
        for (int m = 0; m < 4; ++m) {
            int row0 = m0 + wr + m*16 + g*4;
            if (storemode == 2) {                  // V^T: 4 consecutive s -> 8B pack
                ushort4 pk;
                unsigned short* pp = (unsigned short*)&pk;
                #pragma unroll
                for (int r = 0; r < 4; ++r) pp[r] = f2b(acc[m][n][r] + bv);
                const int hh = col >> 6, d = col & 63;
                const int bb = row0 >> 11, ss = row0 & 2047;
                *(ushort4*)((unsigned short*)out +
                    (((size_t)(bb * CNH + hh)) * CDH + d) * CS + ss) = pk;
            } else {
                #pragma unroll
                for (int r = 0; r < 4; ++r) {
                    int row = row0 + r;
                    float v = (acc[m][n][r] + bv) * oscale;
                    if (GELU) {
                        float a = 0.79788456080286541f * (v + 0.044715f * v * v * v);
                        v = v * (1.0f / (1.0f + __expf(-2.0f * a)));   // 0.5v(1+tanh)
                    }
                    if (RESID) v += b2f(resid[(size_t)row * N + col]);
                    size_t oidx;
                    if (storemode == 1) {
                        int hh = col >> 6, d = col & 63;
                        int bb = row >> 11, ss = row & 2047;
                        oidx = ((((size_t)bb * CNH + hh) * CS) + ss) * CDH + d;
                    } else {
                        oidx = (size_t)row * N + col;
                    }
                    if (OUTDYN && of32dyn) ((float*)out)[oidx] = v;
                    else                   ((unsigned short*)out)[oidx] = f2b(v);
                }
            }
        }
    }
}

// grids: blockIdx.x = m (fast; disjoint per-XCD A tiles), y = n, z = projection.
__global__ __launch_bounds__(256) void k_qkv(
    const unsigned short* __restrict__ xhat,
    const unsigned short* Wq, const float* bq, unsigned short* q,
    const unsigned short* Wk, const float* bk, unsigned short* k,
    const unsigned short* Wv, const float* bv, unsigned short* v)
{
    const unsigned short* W  = blockIdx.z == 0 ? Wq : (blockIdx.z == 1 ? Wk : Wv);
    const float*          bi = blockIdx.z == 0 ? bq : (blockIdx.z == 1 ? bk : bv);
    unsigned short*       o  = blockIdx.z == 0 ? q  : (blockIdx.z == 1 ? k  : v);
    const float osc = blockIdx.z == 0 ? QSCALE : 1.0f;     // fold log2e/sqrt(DH) into Q
    const int sm = blockIdx.z == 2 ? 2 : 1;                // V stored transposed
    gemm_core<false, false, false>(xhat, W, bi, nullptr, o, nullptr,
                                   CH, CH, blockIdx.x * 128, blockIdx.y * 128, osc, sm);
}

__global__ __launch_bounds__(256) void k_oproj(
    const unsigned short* __restrict__ A, const unsigned short* __restrict__ W,
    const float* __restrict__ bias, const unsigned short* __restrict__ resid,
    unsigned short* __restrict__ out)
{
    gemm_core<false, true, false>(A, W, bias, resid, out, nullptr,
                                  CH, CH, blockIdx.x * 128, blockIdx.y * 128, 1.0f, 0);
}

__global__ __launch_bounds__(256) void k_ffn1(
    const unsigned short* __restrict__ A, const unsigned short* __restrict__ W,
    const float* __restrict__ bias, unsigned short* __restrict__ out)
{
    gemm_core<true, false, false>(A, W, bias, nullptr, out, nullptr,
                                  CH, 4*CH, blockIdx.x * 128, blockIdx.y * 128, 1.0f, 0);
}

__global__ __launch_bounds__(256) void k_ffn2(
    const unsigned short* __restrict__ A, const unsigned short* __restrict__ W,
    const float* __restrict__ bias, const unsigned short* __restrict__ resid,
    void* __restrict__ out, const int* __restrict__ flag)
{
    gemm_core<false, true, true>(A, W, bias, resid, out, flag,
                                 4*CH, CH, blockIdx.x * 128, blockIdx.y * 128, 1.0f, 0);
}

// ---------------- Flash attention: 1024 thr / 16 waves = 4 qb x 4 kh --------------
// QBLK=128, KVBLK=128, kh quarters of 32 k. 2 blocks/CU x 16 waves = 32 waves/CU
// (hardware max TLP). Swapped QK^T keeps P in registers; cvt_pk+permlane32_swap
// builds PV A-frags; K/V via global_load_lds chunked dbuf (conflict-free b128).
__global__ __launch_bounds__(1024, 8) void attn_kernel(
    const unsigned short* __restrict__ Q, const unsigned short* __restrict__ Kp,
    const unsigned short* __restrict__ Vt, const int* __restrict__ mask,
    unsigned short* __restrict__ out)
{
    // K dbuf: [2][8 dchunk][128 k][16B] @ 0,16384
    // V dbuf: [2][16 kchunk][64 d][16B] @ 32768,49152
    // endgame: Oex f32[4qb][32q][64d] @ 0 (32KB); lsum f32[4qb][4kh][32q] @ 32768
    __shared__ __align__(16) char lds[65536];

    const int tid = threadIdx.x, lane = tid & 63, wave = tid >> 6;
    const int qb = wave >> 2, kh = wave & 3;
    const int r32 = lane & 31, hi = lane >> 5;
    const int bh = blockIdx.y, bb = bh >> 2, hh = bh & 3;
    const int q0 = blockIdx.x * 128;
    const size_t baseQ = (size_t)bh * CS * CDH;   // Q,K: [S][DH]
    const size_t baseT = (size_t)bh * CDH * CS;   // Vt:  [DH][S]

    // ---- Q fragments in registers (B-operand: col=q, k-chunk = dw*16+hi*8) ----
    const int qrow = q0 + qb * 32 + r32;
    bf16x8 qf[4];
    {
        const bool live = (mask[bb * CS + qrow] != 0);
        #pragma unroll
        for (int dw = 0; dw < 4; ++dw) {
            uint4 v = {0u, 0u, 0u, 0u};
            if (live) v = *(const uint4*)(Q + baseQ + (size_t)qrow * CDH + dw * 16 + hi * 8);
            qf[dw] = *(bf16x8*)&v;
        }
    }

    // staging: 1024 16B slots each for K and V; thread t owns slot t (1 K + 1 V)
#define STAGE(BUF, KT) do {                                                             \
        const int kw = tid >> 7, kk2 = tid & 127;                                       \
        GLOAD_LDS16(Kp + baseQ + (size_t)((KT) + kk2) * CDH + kw * 8,                   \
                    lds + (BUF) * 16384 + wave * 1024);                                 \
        const int vc = tid >> 6, vd = tid & 63;                                         \
        GLOAD_LDS16(Vt + baseT + (size_t)vd * CS + (KT) + vc * 8,                       \
                    lds + 32768 + (BUF) * 16384 + wave * 1024);                         \
    } while (0)

    f32x16 o0 = zero16(), o1 = zero16();
    float psum = 0.f;

    STAGE(0, 0);
    __syncthreads();

    for (int t = 0; t < CS / 128; ++t) {
        const int buf = t & 1;
        const int kt = t * 128;
        if (t + 1 < CS / 128) STAGE(buf ^ 1, kt + 128);

        const char* kbase = lds + buf * 16384;
        const char* vbase = lds + 32768 + buf * 16384;

        // ---- QK^T swapped: sT = S^T[k=kh*32+crow][q=r32] (one 32-k group) ----
        f32x16 sT = zero16();
        __builtin_amdgcn_s_setprio(1);
        #pragma unroll
        for (int dw = 0; dw < 4; ++dw) {
            const char* cb = kbase + (dw * 2 + hi) * 2048;
            bf16x8 k0 = *(const bf16x8*)(cb + (kh * 32 + r32) * 16);
            sT = mfma32(k0, qf[dw], sT);
        }
        __builtin_amdgcn_s_setprio(0);

        // ---- p = exp2(s); pack; permlane -> PV A-frags; PV MFMA ----
        float p[16];
        #pragma unroll
        for (int r = 0; r < 16; ++r) { p[r] = fexp2(sT[r]); psum += p[r]; }
        __builtin_amdgcn_s_setprio(1);
        #pragma unroll
        for (int w = 0; w < 2; ++w) {
            unsigned int a01 = packbf(p[w*8+0], p[w*8+1]);
            unsigned int a23 = packbf(p[w*8+2], p[w*8+3]);
            unsigned int b01 = packbf(p[w*8+4], p[w*8+5]);
            unsigned int b23 = packbf(p[w*8+6], p[w*8+7]);
            i32x2 s1 = __builtin_amdgcn_permlane32_swap((int)a01, (int)b01, false, false);
            i32x2 s2 = __builtin_amdgcn_permlane32_swap((int)a23, (int)b23, false, false);
            union { unsigned int u[4]; bf16x8 v; } apv;
            apv.u[0] = (unsigned int)s1.x; apv.u[1] = (unsigned int)s2.x;
            apv.u[2] = (unsigned int)s1.y; apv.u[3] = (unsigned int)s2.y;
            const char* vb2 = vbase + (kh * 4 + w * 2 + hi) * 1024;
            bf16x8 v0 = *(const bf16x8*)(vb2 + r32 * 16);
            bf16x8 v1 = *(const bf16x8*)(vb2 + (32 + r32) * 16);
            o0 = mfma32(apv.v, v0, o0);
            o1 = mfma32(apv.v, v1, o1);
        }
        __builtin_amdgcn_s_setprio(0);

        __syncthreads();   // staged buf^1 complete (vmcnt drain) + all reads of buf done
    }

    // ---- endgame: 4-way kh reduction via LDS (Oex) + lsum ----
    float ps = psum + __shfl_xor(psum, 32, 64);     // this kh's 32-k sum for q=qb*32+r32
    float* lsum = (float*)(lds + 32768);            // [4qb][4kh][32q]
    float* Oex  = (float*)lds;                      // [4qb][32q][64d]
    if (lane < 32) lsum[(qb * 4 + kh) * 32 + r32] = ps;
    if (kh == 0) {
        #pragma unroll
        for (int r = 0; r < 16; ++r) {
            const int qr = (r & 3) + 8 * (r >> 2) + 4 * hi;
            Oex[(qb * 32 + qr) * 64 + r32]      = o0[r];
            Oex[(qb * 32 + qr) * 64 + 32 + r32] = o1[r];
        }
    }
    __syncthreads();
    #pragma unroll
    for (int c = 1; c < 4; ++c) {
        if (kh == c) {
            #pragma unroll
            for (int r = 0; r < 16; ++r) {
                const int qr = (r & 3) + 8 * (r >> 2) + 4 * hi;
                Oex[(qb * 32 + qr) * 64 + r32]      += o0[r];
                Oex[(qb * 32 + qr) * 64 + 32 + r32] += o1[r];
            }
        }
        __syncthreads();
    }
    if (kh == 0) {
        #pragma unroll
        for (int r = 0; r < 16; ++r) {
            const int qr = (r & 3) + 8 * (r >> 2) + 4 * hi;
            const float l = lsum[(qb * 4 + 0) * 32 + qr] + lsum[(qb * 4 + 1) * 32 + qr]
                          + lsum[(qb * 4 + 2) * 32 + qr] + lsum[(qb * 4 + 3) * 32 + qr];
            const float inv = 1.0f / l;
            const float u0 = Oex[(qb * 32 + qr) * 64 + r32]      * inv;
            const float u1 = Oex[(qb * 32 + qr) * 64 + 32 + r32] * inv;
            const size_t ob = (size_t)(bb * CS + q0 + qb * 32 + qr) * CH + hh * CDH;
            out[ob + r32]      = f2b(u0);
            out[ob + 32 + r32] = f2b(u1);
        }
    }
#undef STAGE
}

// ----------------------------------------------------------------------------------
extern "C" void kernel_launch(void* const* d_in, const int* in_sizes, int n_in,
                              void* d_out, int out_size, void* d_ws, size_t ws_size,
                              hipStream_t stream)
{
    const void* hidden = d_in[0];
    const void* Wq = d_in[1];  const void* bq = d_in[2];
    const void* Wk = d_in[3];  const void* bk = d_in[4];
    const void* Wv = d_in[5];  const void* bv = d_in[6];
    const void* Wo = d_in[7];  const void* bo = d_in[8];
    const void* W1 = d_in[9];  const void* b1 = d_in[10];
    const void* W2 = d_in[11]; const void* b2 = d_in[12];
    const void* ln1w = d_in[13]; const void* ln1b = d_in[14];
    const void* ln2w = d_in[15]; const void* ln2b = d_in[16];
    const int* mask = (const int*)d_in[17];

    char* ws = (char*)d_ws;
    const size_t KB = 1u << 10, MB = 1u << 20;
    int*            flag  = (int*)ws;
    float*          bqf   = (float*)(ws + 4*KB);
    float*          bkf   = (float*)(ws + 8*KB);
    float*          bvf   = (float*)(ws + 12*KB);
    float*          bof   = (float*)(ws + 16*KB);
    float*          b1f   = (float*)(ws + 20*KB);
    float*          b2f_  = (float*)(ws + 28*KB);
    float*          ln1wf = (float*)(ws + 32*KB);
    float*          ln1bf = (float*)(ws + 36*KB);
    float*          ln2wf = (float*)(ws + 40*KB);
    float*          ln2bf = (float*)(ws + 44*KB);
    unsigned short* Wqb   = (unsigned short*)(ws + 1*MB);
    unsigned short* Wkb   = (unsigned short*)(ws + 1*MB + 256*KB);
    unsigned short* Wvb   = (unsigned short*)(ws + 1*MB + 512*KB);
    unsigned short* Wob   = (unsigned short*)(ws + 1*MB + 768*KB);
    unsigned short* W1b   = (unsigned short*)(ws + 2*MB);
    unsigned short* W2b   = (unsigned short*)(ws + 2*MB + 512*KB);
    unsigned short* hb16  = (unsigned short*)(ws + 3*MB);   // [T][H] bf16, 8MB
    unsigned short* xhat  = (unsigned short*)(ws + 11*MB);  // 8MB
    unsigned short* qb    = (unsigned short*)(ws + 19*MB);  // 8MB
    unsigned short* kb    = (unsigned short*)(ws + 27*MB);  // 8MB
    unsigned short* vtb   = (unsigned short*)(ws + 35*MB);  // 8MB (V stored transposed)
    unsigned short* attnb = xhat;                           // xhat dead after QKV
    unsigned short* hid2b = qb;                             // qb dead after attn
    unsigned short* yhat  = kb;                             // kb dead after attn
    unsigned short* h1g   = (unsigned short*)(ws + 51*MB);  // [T][1024] bf16, 32MB

    dim3 blk(256);
    detect_kernel<<<1, blk, 0, stream>>>((const unsigned short*)hidden, flag);

    CvtW cw;
    cw.src[0]=Wq;  cw.dst[0]=Wqb;  cw.n[0]=CH*CH;
    cw.src[1]=Wk;  cw.dst[1]=Wkb;  cw.n[1]=CH*CH;
    cw.src[2]=Wv;  cw.dst[2]=Wvb;  cw.n[2]=CH*CH;
    cw.src[3]=Wo;  cw.dst[3]=Wob;  cw.n[3]=CH*CH;
    cw.src[4]=W1;  cw.dst[4]=W1b;  cw.n[4]=4*CH*CH;
    cw.src[5]=W2;  cw.dst[5]=W2b;  cw.n[5]=4*CH*CH;
    cw.src[6]=hidden; cw.dst[6]=hb16; cw.n[6]=CT*CH;
    cvt_wb_k<<<dim3(256, 7), blk, 0, stream>>>(flag, cw);

    CvtB cf;
    cf.src[0]=bq;    cf.dst[0]=bqf;   cf.n[0]=CH;
    cf.src[1]=bk;    cf.dst[1]=bkf;   cf.n[1]=CH;
    cf.src[2]=bv;    cf.dst[2]=bvf;   cf.n[2]=CH;
    cf.src[3]=bo;    cf.dst[3]=bof;   cf.n[3]=CH;
    cf.src[4]=b1;    cf.dst[4]=b1f;   cf.n[4]=4*CH;
    cf.src[5]=b2;    cf.dst[5]=b2f_;  cf.n[5]=CH;
    cf.src[6]=ln1w;  cf.dst[6]=ln1wf; cf.n[6]=CH;
    cf.src[7]=ln1b;  cf.dst[7]=ln1bf; cf.n[7]=CH;
    cf.src[8]=ln2w;  cf.dst[8]=ln2wf; cf.n[8]=CH;
    cf.src[9]=ln2b;  cf.dst[9]=ln2bf; cf.n[9]=CH;
    cvt_bf_k<<<dim3(1, 10), blk, 0, stream>>>(flag, cf);

    ln_kernel<<<CT / 4, blk, 0, stream>>>(hb16, ln1wf, ln1bf, xhat);
    k_qkv<<<dim3(CT / 128, CH / 128, 3), blk, 0, stream>>>(xhat, Wqb, bqf, qb,
                                                           Wkb, bkf, kb, Wvb, bvf, vtb);
    attn_kernel<<<dim3(CS / 128, CB * CNH), dim3(1024), 0, stream>>>(qb, kb, vtb, mask, attnb);
    k_oproj<<<dim3(CT / 128, CH / 128), blk, 0, stream>>>(attnb, Wob, bof, hb16, hid2b);
    ln_kernel<<<CT / 4, blk, 0, stream>>>(hid2b, ln2wf, ln2bf, yhat);
    k_ffn1<<<dim3(CT / 128, (4 * CH) / 128), blk, 0, stream>>>(yhat, W1b, b1f, h1g);
    k_ffn2<<<dim3(CT / 128, CH / 128), blk, 0, stream>>>(h1g, W2b, b2f_, hid2b,
                                                         d_out, flag);
}

// Round 13
// 164.268 us; speedup vs baseline: 2.5322x; 2.5322x over previous
//
#include <hip/hip_runtime.h>
#include <hip/hip_bf16.h>
#include <cstdint>
#include <cstddef>

constexpr int CB  = 8;
constexpr int CS  = 2048;
constexpr int CH  = 256;
constexpr int CNH = 4;
constexpr int CDH = 64;
constexpr int CT  = CB * CS;   // 16384 tokens

typedef __attribute__((ext_vector_type(8)))  __bf16 bf16x8;
typedef __attribute__((ext_vector_type(4)))  float  f32x4;
typedef __attribute__((ext_vector_type(16))) float  f32x16;
typedef __attribute__((ext_vector_type(2)))  int    i32x2;

__device__ __forceinline__ float b2f(unsigned short u) {
    union { float f; unsigned int i; } v; v.i = ((unsigned int)u) << 16; return v.f;
}
__device__ __forceinline__ unsigned short f2b(float f) {
    union { float f; unsigned int i; } v; v.f = f;
    unsigned int r = v.i + 0x7FFFu + ((v.i >> 16) & 1u);
    return (unsigned short)(r >> 16);
}
__device__ __forceinline__ unsigned short f2b_fast(float f) {  // round-half-up
    union { float f; unsigned int i; } v; v.f = f;
    return (unsigned short)((v.i + 0x8000u) >> 16);
}
__device__ __forceinline__ unsigned int packbf(float a, float b) {
    return (unsigned int)f2b_fast(a) | ((unsigned int)f2b_fast(b) << 16);
}
__device__ __forceinline__ float fexp2(float x) {
#if __has_builtin(__builtin_amdgcn_exp2f)
    return __builtin_amdgcn_exp2f(x);
#else
    float r; asm("v_exp_f32 %0, %1" : "=v"(r) : "v"(x)); return r;
#endif
}
__device__ __forceinline__ f32x4 mfma16(bf16x8 a, bf16x8 b, f32x4 c) {
    return __builtin_amdgcn_mfma_f32_16x16x32_bf16(a, b, c, 0, 0, 0);
}
__device__ __forceinline__ f32x16 mfma32(bf16x8 a, bf16x8 b, f32x16 c) {
    return __builtin_amdgcn_mfma_f32_32x32x16_bf16(a, b, c, 0, 0, 0);
}
__device__ __forceinline__ f32x16 zero16() {
    f32x16 z;
    #pragma unroll
    for (int i = 0; i < 16; ++i) z[i] = 0.f;
    return z;
}

#define GLOAD_LDS16(gptr, lptr)                                                        \
    __builtin_amdgcn_global_load_lds((const __attribute__((address_space(1))) void*)(gptr), \
                                     (__attribute__((address_space(3))) void*)(lptr), 16, 0, 0)

// log2(e)/sqrt(DH): folded into Q projection so softmax uses raw exp2
#define QSCALE 0.1803368801111204f

// ---------------- dtype detect: reading f32 data as bf16 yields huge/NaN values ----
__global__ __launch_bounds__(256) void detect_kernel(
    const unsigned short* __restrict__ h, int* __restrict__ flag)
{
    __shared__ int s_bad;
    const int tid = threadIdx.x;
    if (tid == 0) s_bad = 0;
    __syncthreads();
    bool bad = false;
    for (int i = tid; i < 2048; i += 256) {
        float v = b2f(h[i]);
        if (!(fabsf(v) < 1e25f)) bad = true;   // NaN also lands here
    }
    if (bad) s_bad = 1;
    __syncthreads();
    if (tid == 0) *flag = s_bad;               // 1 => buffers are f32, 0 => bf16
}

// ---------------- converters (runtime input dtype via flag) -----------------------
struct CvtW { const void* src[7]; void* dst[7]; int n[7]; };   // -> bf16 (weights+hidden)
struct CvtB { const void* src[10]; void* dst[10]; int n[10]; };// -> f32 (biases/ln, tiny)

__global__ __launch_bounds__(256) void cvt_wb_k(const int* __restrict__ flag, CvtW a)
{
    const int seg = blockIdx.y, n = a.n[seg];
    const bool inf32 = (*flag != 0);
    const float* sf = (const float*)a.src[seg];
    const unsigned short* sb = (const unsigned short*)a.src[seg];
    unsigned short* d = (unsigned short*)a.dst[seg];
    for (int i = (blockIdx.x * 256 + threadIdx.x) * 4; i < n; i += gridDim.x * 1024) {
        ushort4 o;
        if (inf32) {
            float4 v = *(const float4*)(sf + i);
            o.x = f2b(v.x); o.y = f2b(v.y); o.z = f2b(v.z); o.w = f2b(v.w);
        } else {
            o = *(const ushort4*)(sb + i);
        }
        *(ushort4*)(d + i) = o;
    }
}

__global__ __launch_bounds__(256) void cvt_bf_k(const int* __restrict__ flag, CvtB a)
{
    const int seg = blockIdx.y, n = a.n[seg];
    const bool inf32 = (*flag != 0);
    const float* sf = (const float*)a.src[seg];
    const unsigned short* sb = (const unsigned short*)a.src[seg];
    float* d = (float*)a.dst[seg];
    const int i = threadIdx.x * 4;
    if (i < n) {
        float4 o;
        if (inf32) {
            o = *(const float4*)(sf + i);
        } else {
            ushort4 v = *(const ushort4*)(sb + i);
            o.x = b2f(v.x); o.y = b2f(v.y); o.z = b2f(v.z); o.w = b2f(v.w);
        }
        *(float4*)(d + i) = o;
    }
}

// ---------------- LayerNorm: one wave per token (H=256, 4 elems/lane), bf16 in ----
__global__ __launch_bounds__(256) void ln_kernel(
    const unsigned short* __restrict__ x, const float* __restrict__ w,
    const float* __restrict__ b, unsigned short* __restrict__ out)
{
    const int wave = threadIdx.x >> 6, lane = threadIdx.x & 63;
    const int token = blockIdx.x * 4 + wave;
    const int c = lane * 4;
    const size_t rowo = (size_t)token * CH + c;
    ushort4 u = *(const ushort4*)(x + rowo);
    float v0 = b2f(u.x), v1 = b2f(u.y), v2 = b2f(u.z), v3 = b2f(u.w);
    float s = v0 + v1 + v2 + v3;
    float q = v0*v0 + v1*v1 + v2*v2 + v3*v3;
    #pragma unroll
    for (int m = 1; m < 64; m <<= 1) { s += __shfl_xor(s, m, 64); q += __shfl_xor(q, m, 64); }
    float mean = s * (1.0f/256.0f);
    float var  = q * (1.0f/256.0f) - mean*mean;
    float inv  = rsqrtf(var + 1e-12f);
    float4 ww = *(const float4*)(w + c);
    float4 bb = *(const float4*)(b + c);
    ushort4 o;
    o.x = f2b(ww.x * (v0-mean)*inv + bb.x);
    o.y = f2b(ww.y * (v1-mean)*inv + bb.y);
    o.z = f2b(ww.z * (v2-mean)*inv + bb.z);
    o.w = f2b(ww.w * (v3-mean)*inv + bb.w);
    *(ushort4*)(out + rowo) = o;
}

// ---------------- 128x128 bf16 MFMA GEMM (round-5 proven structure, BK=32) --------
// A:[M][K] W:[N][K] bf16; bias f32; resid bf16. 4 waves, each 64x64 (4x4 frags).
// storemode: 0=row, 1=head ([B][NH][S][DH]), 2=V^T ([B][NH][DH][S], 8B packed).
template<bool GELU, bool RESID, bool OUTDYN>
__device__ __forceinline__ void gemm_core(
    const unsigned short* __restrict__ A, const unsigned short* __restrict__ W,
    const float* __restrict__ bias, const unsigned short* __restrict__ resid,
    void* __restrict__ out, const int* __restrict__ flag,
    int K, int N, int m0, int n0, float oscale, int storemode)
{
    __shared__ __align__(16) unsigned short lA[128*32];
    __shared__ __align__(16) unsigned short lB[128*32];
    const int tid  = threadIdx.x;
    const int lane = tid & 63;
    const int wave = tid >> 6;
    const int wr = (wave >> 1) * 64;
    const int wc = (wave & 1) * 64;
    const int g = lane >> 4, r16 = lane & 15;
    const int lrow = lane >> 2;        // 0..15 rows within 1KB chunk
    const int lch  = lane & 3;         // 16B chunk within 64B row

    const f32x4 zero = {0.f, 0.f, 0.f, 0.f};
    f32x4 acc[4][4];
    #pragma unroll
    for (int m = 0; m < 4; ++m)
        #pragma unroll
        for (int n = 0; n < 4; ++n) acc[m][n] = zero;

    for (int k0 = 0; k0 < K; k0 += 32) {
        #pragma unroll
        for (int i = 0; i < 2; ++i) {
            int chunk = wave + i * 4;              // 0..7 (1KB chunks of 8KB tile)
            int row = chunk * 16 + lrow;           // tile row
            const unsigned short* ga = A + (size_t)(m0 + row) * K + k0 + lch * 8;
            GLOAD_LDS16(ga, &lA[chunk * 512]);
            const unsigned short* gw = W + (size_t)(n0 + row) * K + k0 + lch * 8;
            GLOAD_LDS16(gw, &lB[chunk * 512]);
        }
        __syncthreads();
        bf16x8 af[4], wf[4];
        #pragma unroll
        for (int m = 0; m < 4; ++m) af[m] = *(const bf16x8*)&lA[(wr + m*16 + r16) * 32 + g * 8];
        #pragma unroll
        for (int n = 0; n < 4; ++n) wf[n] = *(const bf16x8*)&lB[(wc + n*16 + r16) * 32 + g * 8];
        #pragma unroll
        for (int m = 0; m < 4; ++m)
            #pragma unroll
            for (int n = 0; n < 4; ++n)
                acc[m][n] = mfma16(af[m], wf[n], acc[m][n]);
        __syncthreads();
    }

    const bool of32dyn = OUTDYN ? (*flag != 0) : false;
    #pragma unroll
    for (int n = 0; n < 4; ++n) {
        int col = n0 + wc + n*16 + r16;
        float bv = bias[col];
        #pragma unroll
        for (int m = 0; m < 4; ++m) {
            int row0 = m0 + wr + m*16 + g*4;
            if (storemode == 2) {                  // V^T: 4 consecutive s -> 8B pack
                ushort4 pk;
                unsigned short* pp = (unsigned short*)&pk;
                #pragma unroll
                for (int r = 0; r < 4; ++r) pp[r] = f2b(acc[m][n][r] + bv);
                const int hh = col >> 6, d = col & 63;
                const int bb = row0 >> 11, ss = row0 & 2047;
                *(ushort4*)((unsigned short*)out +
                    (((size_t)(bb * CNH + hh)) * CDH + d) * CS + ss) = pk;
            } else {
                #pragma unroll
                for (int r = 0; r < 4; ++r) {
                    int row = row0 + r;
                    float v = (acc[m][n][r] + bv) * oscale;
                    if (GELU) {
                        float a = 0.79788456080286541f * (v + 0.044715f * v * v * v);
                        v = v * (1.0f / (1.0f + __expf(-2.0f * a)));   // 0.5v(1+tanh)
                    }
                    if (RESID) v += b2f(resid[(size_t)row * N + col]);
                    size_t oidx;
                    if (storemode == 1) {
                        int hh = col >> 6, d = col & 63;
                        int bb = row >> 11, ss = row & 2047;
                        oidx = ((((size_t)bb * CNH + hh) * CS) + ss) * CDH + d;
                    } else {
                        oidx = (size_t)row * N + col;
                    }
                    if (OUTDYN && of32dyn) ((float*)out)[oidx] = v;
                    else                   ((unsigned short*)out)[oidx] = f2b(v);
                }
            }
        }
    }
}

// grids: blockIdx.x = m (fast; disjoint per-XCD A tiles), y = n, z = projection.
__global__ __launch_bounds__(256) void k_qkv(
    const unsigned short* __restrict__ xhat,
    const unsigned short* Wq, const float* bq, unsigned short* q,
    const unsigned short* Wk, const float* bk, unsigned short* k,
    const unsigned short* Wv, const float* bv, unsigned short* v)
{
    const unsigned short* W  = blockIdx.z == 0 ? Wq : (blockIdx.z == 1 ? Wk : Wv);
    const float*          bi = blockIdx.z == 0 ? bq : (blockIdx.z == 1 ? bk : bv);
    unsigned short*       o  = blockIdx.z == 0 ? q  : (blockIdx.z == 1 ? k  : v);
    const float osc = blockIdx.z == 0 ? QSCALE : 1.0f;     // fold log2e/sqrt(DH) into Q
    const int sm = blockIdx.z == 2 ? 2 : 1;                // V stored transposed
    gemm_core<false, false, false>(xhat, W, bi, nullptr, o, nullptr,
                                   CH, CH, blockIdx.x * 128, blockIdx.y * 128, osc, sm);
}

__global__ __launch_bounds__(256) void k_oproj(
    const unsigned short* __restrict__ A, const unsigned short* __restrict__ W,
    const float* __restrict__ bias, const unsigned short* __restrict__ resid,
    unsigned short* __restrict__ out)
{
    gemm_core<false, true, false>(A, W, bias, resid, out, nullptr,
                                  CH, CH, blockIdx.x * 128, blockIdx.y * 128, 1.0f, 0);
}

__global__ __launch_bounds__(256) void k_ffn1(
    const unsigned short* __restrict__ A, const unsigned short* __restrict__ W,
    const float* __restrict__ bias, unsigned short* __restrict__ out)
{
    gemm_core<true, false, false>(A, W, bias, nullptr, out, nullptr,
                                  CH, 4*CH, blockIdx.x * 128, blockIdx.y * 128, 1.0f, 0);
}

__global__ __launch_bounds__(256) void k_ffn2(
    const unsigned short* __restrict__ A, const unsigned short* __restrict__ W,
    const float* __restrict__ bias, const unsigned short* __restrict__ resid,
    void* __restrict__ out, const int* __restrict__ flag)
{
    gemm_core<false, true, true>(A, W, bias, resid, out, flag,
                                 4*CH, CH, blockIdx.x * 128, blockIdx.y * 128, 1.0f, 0);
}

// ---------------- Flash attention, 32x32 MFMA, in-register P (round-5 proven) -----
// 512 thr / 8 waves = 4 q-blocks(32) x 2 k-halves(64). QBLK=128, KVBLK=128.
// Swapped QK^T (mfma(K,Q)) puts P in registers per q-col; cvt_pk+permlane32_swap
// builds PV A-fragments with ZERO P LDS traffic. K/V staged via global_load_lds
// into chunked layouts (conflict-free b128 reads), double-buffered.
__global__ __launch_bounds__(512, 4) void attn_kernel(
    const unsigned short* __restrict__ Q, const unsigned short* __restrict__ Kp,
    const unsigned short* __restrict__ Vt, const int* __restrict__ mask,
    unsigned short* __restrict__ out)
{
    // K dbuf: [2][8 dchunk][128 k][16B] @ 0,16384
    // V dbuf: [2][16 kchunk][64 d][16B] @ 32768,49152
    // after loop: Oex f32[4][32][64] @ 0 ; lsum f32[4][2][32] @ 32768
    __shared__ __align__(16) char lds[65536];

    const int tid = threadIdx.x, lane = tid & 63, wave = tid >> 6;
    const int qb = wave >> 1, kh = wave & 1;
    const int r32 = lane & 31, hi = lane >> 5;
    const int bh = blockIdx.y, bb = bh >> 2, hh = bh & 3;
    const int q0 = blockIdx.x * 128;
    const size_t baseQ = (size_t)bh * CS * CDH;   // Q,K: [S][DH]
    const size_t baseT = (size_t)bh * CDH * CS;   // Vt:  [DH][S]

    // ---- Q fragments in registers (B-operand: col=q, k-chunk = dw*16+hi*8) ----
    const int qrow = q0 + qb * 32 + r32;
    bf16x8 qf[4];
    {
        const bool live = (mask[bb * CS + qrow] != 0);
        #pragma unroll
        for (int dw = 0; dw < 4; ++dw) {
            uint4 v = {0u, 0u, 0u, 0u};
            if (live) v = *(const uint4*)(Q + baseQ + (size_t)qrow * CDH + dw * 16 + hi * 8);
            qf[dw] = *(bf16x8*)&v;
        }
    }

    // staging: 1024 16B slots each for K and V; wave w covers slots [w*64+i*512 .. +63]
#define STAGE(BUF, KT) do {                                                             \
        _Pragma("unroll")                                                               \
        for (int i = 0; i < 2; ++i) {                                                   \
            const int slot0 = i * 512 + wave * 64;                                      \
            const int slot  = slot0 + lane;                                             \
            const int kw = slot >> 7, kk2 = slot & 127;                                 \
            GLOAD_LDS16(Kp + baseQ + (size_t)((KT) + kk2) * CDH + kw * 8,               \
                        lds + (BUF) * 16384 + slot0 * 16);                              \
            const int vc = slot >> 6, vd = slot & 63;                                   \
            GLOAD_LDS16(Vt + baseT + (size_t)vd * CS + (KT) + vc * 8,                   \
                        lds + 32768 + (BUF) * 16384 + slot0 * 16);                      \
        } } while (0)

    f32x16 o0 = zero16(), o1 = zero16();
    float psum = 0.f;

    STAGE(0, 0);
    __syncthreads();

    for (int t = 0; t < CS / 128; ++t) {
        const int buf = t & 1;
        const int kt = t * 128;
        if (t + 1 < CS / 128) STAGE(buf ^ 1, kt + 128);

        const char* kbase = lds + buf * 16384;
        const char* vbase = lds + 32768 + buf * 16384;

        // ---- QK^T swapped: sT[kb] = S^T[k=kh*64+kb*32+crow][q=r32] ----
        f32x16 sT0 = zero16(), sT1 = zero16();
        __builtin_amdgcn_s_setprio(1);
        #pragma unroll
        for (int dw = 0; dw < 4; ++dw) {
            const char* cb = kbase + (dw * 2 + hi) * 2048;
            bf16x8 k0 = *(const bf16x8*)(cb + (kh * 64 + r32) * 16);
            bf16x8 k1 = *(const bf16x8*)(cb + (kh * 64 + 32 + r32) * 16);
            sT0 = mfma32(k0, qf[dw], sT0);
            sT1 = mfma32(k1, qf[dw], sT1);
        }
        __builtin_amdgcn_s_setprio(0);

        // ---- p=exp2(s); cvt_pk; permlane -> PV A-frags; PV MFMA; no LDS for P ----
#define PROCKB(SREG, KB) do {                                                           \
            float p[16];                                                                \
            _Pragma("unroll")                                                           \
            for (int r = 0; r < 16; ++r) { p[r] = fexp2((SREG)[r]); psum += p[r]; }     \
            _Pragma("unroll")                                                           \
            for (int w = 0; w < 2; ++w) {                                               \
                unsigned int a01 = packbf(p[w*8+0], p[w*8+1]);                          \
                unsigned int a23 = packbf(p[w*8+2], p[w*8+3]);                          \
                unsigned int b01 = packbf(p[w*8+4], p[w*8+5]);                          \
                unsigned int b23 = packbf(p[w*8+6], p[w*8+7]);                          \
                unsigned int ap0, ap1, ap2, ap3;                                        \
                {                                                                       \
                    i32x2 s1 = __builtin_amdgcn_permlane32_swap((int)a01, (int)b01, false, false); \
                    i32x2 s2 = __builtin_amdgcn_permlane32_swap((int)a23, (int)b23, false, false); \
                    ap0 = (unsigned int)s1.x; ap2 = (unsigned int)s1.y;                 \
                    ap1 = (unsigned int)s2.x; ap3 = (unsigned int)s2.y;                 \
                }                                                                       \
                union { unsigned int u[4]; bf16x8 v; } apv;                             \
                apv.u[0] = ap0; apv.u[1] = ap1; apv.u[2] = ap2; apv.u[3] = ap3;         \
                const char* vb2 = vbase + ((kh * 4 + (KB) * 2 + w) * 2 + hi) * 1024;    \
                bf16x8 v0 = *(const bf16x8*)(vb2 + r32 * 16);                           \
                bf16x8 v1 = *(const bf16x8*)(vb2 + (32 + r32) * 16);                    \
                o0 = mfma32(apv.v, v0, o0);                                             \
                o1 = mfma32(apv.v, v1, o1);                                             \
            } } while (0)

        PROCKB(sT0, 0);
        PROCKB(sT1, 1);
#undef PROCKB

        __syncthreads();   // staged buf^1 complete (vmcnt drain) + all reads of buf done
    }

    // ---- end reduction: cross-hi psum, cross-kh O and l via LDS ----
    float ps = psum + __shfl_xor(psum, 32, 64);     // full k-half sum for q=qb*32+r32
    float* lsum = (float*)(lds + 32768);            // [4][2][32]
    float* Oex  = (float*)lds;                      // [4][32][64]
    if (lane < 32) lsum[(qb * 2 + kh) * 32 + r32] = ps;
    if (kh == 1) {
        #pragma unroll
        for (int r = 0; r < 16; ++r) {
            const int qr = (r & 3) + 8 * (r >> 2) + 4 * hi;
            Oex[(qb * 32 + qr) * 64 + r32]      = o0[r];
            Oex[(qb * 32 + qr) * 64 + 32 + r32] = o1[r];
        }
    }
    __syncthreads();
    if (kh == 0) {
        #pragma unroll
        for (int r = 0; r < 16; ++r) {
            const int qr = (r & 3) + 8 * (r >> 2) + 4 * hi;
            const float l = lsum[(qb * 2 + 0) * 32 + qr] + lsum[(qb * 2 + 1) * 32 + qr];
            const float inv = 1.0f / l;
            const float u0 = (o0[r] + Oex[(qb * 32 + qr) * 64 + r32]) * inv;
            const float u1 = (o1[r] + Oex[(qb * 32 + qr) * 64 + 32 + r32]) * inv;
            const size_t ob = (size_t)(bb * CS + q0 + qb * 32 + qr) * CH + hh * CDH;
            out[ob + r32]      = f2b(u0);
            out[ob + 32 + r32] = f2b(u1);
        }
    }
#undef STAGE
}

// ----------------------------------------------------------------------------------
extern "C" void kernel_launch(void* const* d_in, const int* in_sizes, int n_in,
                              void* d_out, int out_size, void* d_ws, size_t ws_size,
                              hipStream_t stream)
{
    const void* hidden = d_in[0];
    const void* Wq = d_in[1];  const void* bq = d_in[2];
    const void* Wk = d_in[3];  const void* bk = d_in[4];
    const void* Wv = d_in[5];  const void* bv = d_in[6];
    const void* Wo = d_in[7];  const void* bo = d_in[8];
    const void* W1 = d_in[9];  const void* b1 = d_in[10];
    const void* W2 = d_in[11]; const void* b2 = d_in[12];
    const void* ln1w = d_in[13]; const void* ln1b = d_in[14];
    const void* ln2w = d_in[15]; const void* ln2b = d_in[16];
    const int* mask = (const int*)d_in[17];

    char* ws = (char*)d_ws;
    const size_t KB = 1u << 10, MB = 1u << 20;
    int*            flag  = (int*)ws;
    float*          bqf   = (float*)(ws + 4*KB);
    float*          bkf   = (float*)(ws + 8*KB);
    float*          bvf   = (float*)(ws + 12*KB);
    float*          bof   = (float*)(ws + 16*KB);
    float*          b1f   = (float*)(ws + 20*KB);
    float*          b2f_  = (float*)(ws + 28*KB);
    float*          ln1wf = (float*)(ws + 32*KB);
    float*          ln1bf = (float*)(ws + 36*KB);
    float*          ln2wf = (float*)(ws + 40*KB);
    float*          ln2bf = (float*)(ws + 44*KB);
    unsigned short* Wqb   = (unsigned short*)(ws + 1*MB);
    unsigned short* Wkb   = (unsigned short*)(ws + 1*MB + 256*KB);
    unsigned short* Wvb   = (unsigned short*)(ws + 1*MB + 512*KB);
    unsigned short* Wob   = (unsigned short*)(ws + 1*MB + 768*KB);
    unsigned short* W1b   = (unsigned short*)(ws + 2*MB);
    unsigned short* W2b   = (unsigned short*)(ws + 2*MB + 512*KB);
    unsigned short* hb16  = (unsigned short*)(ws + 3*MB);   // [T][H] bf16, 8MB
    unsigned short* xhat  = (unsigned short*)(ws + 11*MB);  // 8MB
    unsigned short* qb    = (unsigned short*)(ws + 19*MB);  // 8MB
    unsigned short* kb    = (unsigned short*)(ws + 27*MB);  // 8MB
    unsigned short* vtb   = (unsigned short*)(ws + 35*MB);  // 8MB (V stored transposed)
    unsigned short* attnb = xhat;                           // xhat dead after QKV
    unsigned short* hid2b = qb;                             // qb dead after attn
    unsigned short* yhat  = kb;                             // kb dead after attn
    unsigned short* h1g   = (unsigned short*)(ws + 51*MB);  // [T][1024] bf16, 32MB

    dim3 blk(256);
    detect_kernel<<<1, blk, 0, stream>>>((const unsigned short*)hidden, flag);

    CvtW cw;
    cw.src[0]=Wq;  cw.dst[0]=Wqb;  cw.n[0]=CH*CH;
    cw.src[1]=Wk;  cw.dst[1]=Wkb;  cw.n[1]=CH*CH;
    cw.src[2]=Wv;  cw.dst[2]=Wvb;  cw.n[2]=CH*CH;
    cw.src[3]=Wo;  cw.dst[3]=Wob;  cw.n[3]=CH*CH;
    cw.src[4]=W1;  cw.dst[4]=W1b;  cw.n[4]=4*CH*CH;
    cw.src[5]=W2;  cw.dst[5]=W2b;  cw.n[5]=4*CH*CH;
    cw.src[6]=hidden; cw.dst[6]=hb16; cw.n[6]=CT*CH;
    cvt_wb_k<<<dim3(256, 7), blk, 0, stream>>>(flag, cw);

    CvtB cf;
    cf.src[0]=bq;    cf.dst[0]=bqf;   cf.n[0]=CH;
    cf.src[1]=bk;    cf.dst[1]=bkf;   cf.n[1]=CH;
    cf.src[2]=bv;    cf.dst[2]=bvf;   cf.n[2]=CH;
    cf.src[3]=bo;    cf.dst[3]=bof;   cf.n[3]=CH;
    cf.src[4]=b1;    cf.dst[4]=b1f;   cf.n[4]=4*CH;
    cf.src[5]=b2;    cf.dst[5]=b2f_;  cf.n[5]=CH;
    cf.src[6]=ln1w;  cf.dst[6]=ln1wf; cf.n[6]=CH;
    cf.src[7]=ln1b;  cf.dst[7]=ln1bf; cf.n[7]=CH;
    cf.src[8]=ln2w;  cf.dst[8]=ln2wf; cf.n[8]=CH;
    cf.src[9]=ln2b;  cf.dst[9]=ln2bf; cf.n[9]=CH;
    cvt_bf_k<<<dim3(1, 10), blk, 0, stream>>>(flag, cf);

    ln_kernel<<<CT / 4, blk, 0, stream>>>(hb16, ln1wf, ln1bf, xhat);
    k_qkv<<<dim3(CT / 128, CH / 128, 3), blk, 0, stream>>>(xhat, Wqb, bqf, qb,
                                                           Wkb, bkf, kb, Wvb, bvf, vtb);
    attn_kernel<<<dim3(CS / 128, CB * CNH), dim3(512), 0, stream>>>(qb, kb, vtb, mask, attnb);
    k_oproj<<<dim3(CT / 128, CH / 128), blk, 0, stream>>>(attnb, Wob, bof, hb16, hid2b);
    ln_kernel<<<CT / 4, blk, 0, stream>>>(hid2b, ln2wf, ln2bf, yhat);
    k_ffn1<<<dim3(CT / 128, (4 * CH) / 128), blk, 0, stream>>>(yhat, W1b, b1f, h1g);
    k_ffn2<<<dim3(CT / 128, CH / 128), blk, 0, stream>>>(h1g, W2b, b2f_, hid2b,
                                                         d_out, flag);
}

// Round 14
// 160.454 us; speedup vs baseline: 2.5923x; 1.0238x over previous
//
#include <hip/hip_runtime.h>
#include <hip/hip_bf16.h>
#include <cstdint>
#include <cstddef>

constexpr int CB  = 8;
constexpr int CS  = 2048;
constexpr int CH  = 256;
constexpr int CNH = 4;
constexpr int CDH = 64;
constexpr int CT  = CB * CS;   // 16384 tokens

typedef __attribute__((ext_vector_type(8)))  __bf16 bf16x8;
typedef __attribute__((ext_vector_type(4)))  float  f32x4;
typedef __attribute__((ext_vector_type(16))) float  f32x16;
typedef __attribute__((ext_vector_type(2)))  int    i32x2;

__device__ __forceinline__ float b2f(unsigned short u) {
    union { float f; unsigned int i; } v; v.i = ((unsigned int)u) << 16; return v.f;
}
__device__ __forceinline__ unsigned short f2b(float f) {
    union { float f; unsigned int i; } v; v.f = f;
    unsigned int r = v.i + 0x7FFFu + ((v.i >> 16) & 1u);
    return (unsigned short)(r >> 16);
}
__device__ __forceinline__ unsigned short f2b_fast(float f) {  // round-half-up
    union { float f; unsigned int i; } v; v.f = f;
    return (unsigned short)((v.i + 0x8000u) >> 16);
}
__device__ __forceinline__ unsigned int packbf(float a, float b) {
    return (unsigned int)f2b_fast(a) | ((unsigned int)f2b_fast(b) << 16);
}
__device__ __forceinline__ float fexp2(float x) {
#if __has_builtin(__builtin_amdgcn_exp2f)
    return __builtin_amdgcn_exp2f(x);
#else
    float r; asm("v_exp_f32 %0, %1" : "=v"(r) : "v"(x)); return r;
#endif
}
__device__ __forceinline__ f32x4 mfma16(bf16x8 a, bf16x8 b, f32x4 c) {
    return __builtin_amdgcn_mfma_f32_16x16x32_bf16(a, b, c, 0, 0, 0);
}
__device__ __forceinline__ f32x16 mfma32(bf16x8 a, bf16x8 b, f32x16 c) {
    return __builtin_amdgcn_mfma_f32_32x32x16_bf16(a, b, c, 0, 0, 0);
}
__device__ __forceinline__ f32x16 zero16() {
    f32x16 z;
    #pragma unroll
    for (int i = 0; i < 16; ++i) z[i] = 0.f;
    return z;
}

#define GLOAD_LDS16(gptr, lptr)                                                        \
    __builtin_amdgcn_global_load_lds((const __attribute__((address_space(1))) void*)(gptr), \
                                     (__attribute__((address_space(3))) void*)(lptr), 16, 0, 0)

// log2(e)/sqrt(DH): folded into Q projection so softmax uses raw exp2
#define QSCALE 0.1803368801111204f

// ---------------- dtype detect: reading f32 data as bf16 yields huge/NaN values ----
__global__ __launch_bounds__(256) void detect_kernel(
    const unsigned short* __restrict__ h, int* __restrict__ flag)
{
    __shared__ int s_bad;
    const int tid = threadIdx.x;
    if (tid == 0) s_bad = 0;
    __syncthreads();
    bool bad = false;
    for (int i = tid; i < 2048; i += 256) {
        float v = b2f(h[i]);
        if (!(fabsf(v) < 1e25f)) bad = true;   // NaN also lands here
    }
    if (bad) s_bad = 1;
    __syncthreads();
    if (tid == 0) *flag = s_bad;               // 1 => buffers are f32, 0 => bf16
}

// ---------------- converters (runtime input dtype via flag) -----------------------
struct CvtW { const void* src[6]; void* dst[6]; int n[6]; };   // -> bf16 (weights)
struct CvtB { const void* src[10]; void* dst[10]; int n[10]; };// -> f32 (biases/ln, tiny)

__global__ __launch_bounds__(256) void cvt_wb_k(const int* __restrict__ flag, CvtW a)
{
    const int seg = blockIdx.y, n = a.n[seg];
    const bool inf32 = (*flag != 0);
    const float* sf = (const float*)a.src[seg];
    const unsigned short* sb = (const unsigned short*)a.src[seg];
    unsigned short* d = (unsigned short*)a.dst[seg];
    for (int i = (blockIdx.x * 256 + threadIdx.x) * 4; i < n; i += gridDim.x * 1024) {
        ushort4 o;
        if (inf32) {
            float4 v = *(const float4*)(sf + i);
            o.x = f2b(v.x); o.y = f2b(v.y); o.z = f2b(v.z); o.w = f2b(v.w);
        } else {
            o = *(const ushort4*)(sb + i);
        }
        *(ushort4*)(d + i) = o;
    }
}

__global__ __launch_bounds__(256) void cvt_bf_k(const int* __restrict__ flag, CvtB a)
{
    const int seg = blockIdx.y, n = a.n[seg];
    const bool inf32 = (*flag != 0);
    const float* sf = (const float*)a.src[seg];
    const unsigned short* sb = (const unsigned short*)a.src[seg];
    float* d = (float*)a.dst[seg];
    const int i = threadIdx.x * 4;
    if (i < n) {
        float4 o;
        if (inf32) {
            o = *(const float4*)(sf + i);
        } else {
            ushort4 v = *(const ushort4*)(sb + i);
            o.x = b2f(v.x); o.y = b2f(v.y); o.z = b2f(v.z); o.w = b2f(v.w);
        }
        *(float4*)(d + i) = o;
    }
}

// ---------------- LN1 fused with input conversion: raw hidden -> xhat + hb16 ------
__global__ __launch_bounds__(256) void ln1_dyn_kernel(
    const void* __restrict__ x, const int* __restrict__ flag,
    const float* __restrict__ w, const float* __restrict__ b,
    unsigned short* __restrict__ xout, unsigned short* __restrict__ hcopy)
{
    const int wave = threadIdx.x >> 6, lane = threadIdx.x & 63;
    const int token = blockIdx.x * 4 + wave;
    const int c = lane * 4;
    const size_t rowo = (size_t)token * CH + c;
    float v0, v1, v2, v3;
    if (*flag != 0) {
        float4 u = *(const float4*)((const float*)x + rowo);
        v0 = u.x; v1 = u.y; v2 = u.z; v3 = u.w;
    } else {
        ushort4 u = *(const ushort4*)((const unsigned short*)x + rowo);
        v0 = b2f(u.x); v1 = b2f(u.y); v2 = b2f(u.z); v3 = b2f(u.w);
    }
    ushort4 hc;
    hc.x = f2b(v0); hc.y = f2b(v1); hc.z = f2b(v2); hc.w = f2b(v3);
    *(ushort4*)(hcopy + rowo) = hc;                 // bf16 residual copy
    float s = v0 + v1 + v2 + v3;
    float q = v0*v0 + v1*v1 + v2*v2 + v3*v3;
    #pragma unroll
    for (int m = 1; m < 64; m <<= 1) { s += __shfl_xor(s, m, 64); q += __shfl_xor(q, m, 64); }
    float mean = s * (1.0f/256.0f);
    float var  = q * (1.0f/256.0f) - mean*mean;
    float inv  = rsqrtf(var + 1e-12f);
    float4 ww = *(const float4*)(w + c);
    float4 bb = *(const float4*)(b + c);
    ushort4 o;
    o.x = f2b(ww.x * (v0-mean)*inv + bb.x);
    o.y = f2b(ww.y * (v1-mean)*inv + bb.y);
    o.z = f2b(ww.z * (v2-mean)*inv + bb.z);
    o.w = f2b(ww.w * (v3-mean)*inv + bb.w);
    *(ushort4*)(xout + rowo) = o;
}

// ---------------- LayerNorm (bf16 in), for LN2 ------------------------------------
__global__ __launch_bounds__(256) void ln_kernel(
    const unsigned short* __restrict__ x, const float* __restrict__ w,
    const float* __restrict__ b, unsigned short* __restrict__ out)
{
    const int wave = threadIdx.x >> 6, lane = threadIdx.x & 63;
    const int token = blockIdx.x * 4 + wave;
    const int c = lane * 4;
    const size_t rowo = (size_t)token * CH + c;
    ushort4 u = *(const ushort4*)(x + rowo);
    float v0 = b2f(u.x), v1 = b2f(u.y), v2 = b2f(u.z), v3 = b2f(u.w);
    float s = v0 + v1 + v2 + v3;
    float q = v0*v0 + v1*v1 + v2*v2 + v3*v3;
    #pragma unroll
    for (int m = 1; m < 64; m <<= 1) { s += __shfl_xor(s, m, 64); q += __shfl_xor(q, m, 64); }
    float mean = s * (1.0f/256.0f);
    float var  = q * (1.0f/256.0f) - mean*mean;
    float inv  = rsqrtf(var + 1e-12f);
    float4 ww = *(const float4*)(w + c);
    float4 bb = *(const float4*)(b + c);
    ushort4 o;
    o.x = f2b(ww.x * (v0-mean)*inv + bb.x);
    o.y = f2b(ww.y * (v1-mean)*inv + bb.y);
    o.z = f2b(ww.z * (v2-mean)*inv + bb.z);
    o.w = f2b(ww.w * (v3-mean)*inv + bb.w);
    *(ushort4*)(out + rowo) = o;
}

// ---------------- 128x128 bf16 MFMA GEMM, BK=32, quarter-swizzled LDS -------------
// A:[M][K] W:[N][K] bf16; bias f32; resid bf16. 4 waves, each 64x64 (4x4 frags).
// LDS rows are 64B; 16B quarter q of row holds global quarter q^((row>>1)&3)
// (source pre-swizzle keeps the 64B-line coalescing; read applies the same XOR).
// Fixes the 8-way ds_read_b128 bank conflict (rows 2 apart aliased banks).
// storemode: 0=row, 1=head ([B][NH][S][DH]), 2=V^T ([B][NH][DH][S], 8B packed).
template<bool GELU, bool RESID, bool OUTDYN>
__device__ __forceinline__ void gemm_core(
    const unsigned short* __restrict__ A, const unsigned short* __restrict__ W,
    const float* __restrict__ bias, const unsigned short* __restrict__ resid,
    void* __restrict__ out, const int* __restrict__ flag,
    int K, int N, int m0, int n0, float oscale, int storemode)
{
    __shared__ __align__(16) unsigned short lA[128*32];
    __shared__ __align__(16) unsigned short lB[128*32];
    const int tid  = threadIdx.x;
    const int lane = tid & 63;
    const int wave = tid >> 6;
    const int wr = (wave >> 1) * 64;
    const int wc = (wave & 1) * 64;
    const int g = lane >> 4, r16 = lane & 15;
    const int lrow = lane >> 2;        // 0..15 rows within 1KB chunk
    const int lch  = lane & 3;         // 16B quarter within 64B row

    const f32x4 zero = {0.f, 0.f, 0.f, 0.f};
    f32x4 acc[4][4];
    #pragma unroll
    for (int m = 0; m < 4; ++m)
        #pragma unroll
        for (int n = 0; n < 4; ++n) acc[m][n] = zero;

    for (int k0 = 0; k0 < K; k0 += 32) {
        #pragma unroll
        for (int i = 0; i < 2; ++i) {
            int chunk = wave + i * 4;              // 0..7 (1KB chunks of 8KB tile)
            int row = chunk * 16 + lrow;           // tile row
            int lq  = lch ^ ((row >> 1) & 3);      // pre-swizzled source quarter
            const unsigned short* ga = A + (size_t)(m0 + row) * K + k0 + lq * 8;
            GLOAD_LDS16(ga, &lA[chunk * 512]);
            const unsigned short* gw = W + (size_t)(n0 + row) * K + k0 + lq * 8;
            GLOAD_LDS16(gw, &lB[chunk * 512]);
        }
        __syncthreads();
        bf16x8 af[4], wf[4];
        #pragma unroll
        for (int m = 0; m < 4; ++m) {
            const int arow = wr + m*16 + r16;
            af[m] = *(const bf16x8*)&lA[arow * 32 + (g ^ ((arow >> 1) & 3)) * 8];
        }
        #pragma unroll
        for (int n = 0; n < 4; ++n) {
            const int brow = wc + n*16 + r16;
            wf[n] = *(const bf16x8*)&lB[brow * 32 + (g ^ ((brow >> 1) & 3)) * 8];
        }
        #pragma unroll
        for (int m = 0; m < 4; ++m)
            #pragma unroll
            for (int n = 0; n < 4; ++n)
                acc[m][n] = mfma16(af[m], wf[n], acc[m][n]);
        __syncthreads();
    }

    const bool of32dyn = OUTDYN ? (*flag != 0) : false;
    #pragma unroll
    for (int n = 0; n < 4; ++n) {
        int col = n0 + wc + n*16 + r16;
        float bv = bias[col];
        #pragma unroll
        for (int m = 0; m < 4; ++m) {
            int row0 = m0 + wr + m*16 + g*4;
            if (storemode == 2) {                  // V^T: 4 consecutive s -> 8B pack
                ushort4 pk;
                unsigned short* pp = (unsigned short*)&pk;
                #pragma unroll
                for (int r = 0; r < 4; ++r) pp[r] = f2b(acc[m][n][r] + bv);
                const int hh = col >> 6, d = col & 63;
                const int bb = row0 >> 11, ss = row0 & 2047;
                *(ushort4*)((unsigned short*)out +
                    (((size_t)(bb * CNH + hh)) * CDH + d) * CS + ss) = pk;
            } else {
                #pragma unroll
                for (int r = 0; r < 4; ++r) {
                    int row = row0 + r;
                    float v = (acc[m][n][r] + bv) * oscale;
                    if (GELU) {
                        float a = 0.79788456080286541f * (v + 0.044715f * v * v * v);
                        v = v * (1.0f / (1.0f + __expf(-2.0f * a)));   // 0.5v(1+tanh)
                    }
                    if (RESID) v += b2f(resid[(size_t)row * N + col]);
                    size_t oidx;
                    if (storemode == 1) {
                        int hh = col >> 6, d = col & 63;
                        int bb = row >> 11, ss = row & 2047;
                        oidx = ((((size_t)bb * CNH + hh) * CS) + ss) * CDH + d;
                    } else {
                        oidx = (size_t)row * N + col;
                    }
                    if (OUTDYN && of32dyn) ((float*)out)[oidx] = v;
                    else                   ((unsigned short*)out)[oidx] = f2b(v);
                }
            }
        }
    }
}

// grids: blockIdx.x = m (fast; disjoint per-XCD A tiles), y = n, z = projection.
__global__ __launch_bounds__(256) void k_qkv(
    const unsigned short* __restrict__ xhat,
    const unsigned short* Wq, const float* bq, unsigned short* q,
    const unsigned short* Wk, const float* bk, unsigned short* k,
    const unsigned short* Wv, const float* bv, unsigned short* v)
{
    const unsigned short* W  = blockIdx.z == 0 ? Wq : (blockIdx.z == 1 ? Wk : Wv);
    const float*          bi = blockIdx.z == 0 ? bq : (blockIdx.z == 1 ? bk : bv);
    unsigned short*       o  = blockIdx.z == 0 ? q  : (blockIdx.z == 1 ? k  : v);
    const float osc = blockIdx.z == 0 ? QSCALE : 1.0f;     // fold log2e/sqrt(DH) into Q
    const int sm = blockIdx.z == 2 ? 2 : 1;                // V stored transposed
    gemm_core<false, false, false>(xhat, W, bi, nullptr, o, nullptr,
                                   CH, CH, blockIdx.x * 128, blockIdx.y * 128, osc, sm);
}

__global__ __launch_bounds__(256) void k_oproj(
    const unsigned short* __restrict__ A, const unsigned short* __restrict__ W,
    const float* __restrict__ bias, const unsigned short* __restrict__ resid,
    unsigned short* __restrict__ out)
{
    gemm_core<false, true, false>(A, W, bias, resid, out, nullptr,
                                  CH, CH, blockIdx.x * 128, blockIdx.y * 128, 1.0f, 0);
}

__global__ __launch_bounds__(256) void k_ffn1(
    const unsigned short* __restrict__ A, const unsigned short* __restrict__ W,
    const float* __restrict__ bias, unsigned short* __restrict__ out)
{
    gemm_core<true, false, false>(A, W, bias, nullptr, out, nullptr,
                                  CH, 4*CH, blockIdx.x * 128, blockIdx.y * 128, 1.0f, 0);
}

__global__ __launch_bounds__(256) void k_ffn2(
    const unsigned short* __restrict__ A, const unsigned short* __restrict__ W,
    const float* __restrict__ bias, const unsigned short* __restrict__ resid,
    void* __restrict__ out, const int* __restrict__ flag)
{
    gemm_core<false, true, true>(A, W, bias, resid, out, flag,
                                 4*CH, CH, blockIdx.x * 128, blockIdx.y * 128, 1.0f, 0);
}

// ---------------- Flash attention, 32x32 MFMA, in-register P (round-5 proven) -----
// 512 thr / 8 waves = 4 q-blocks(32) x 2 k-halves(64). QBLK=128, KVBLK=128.
// Swapped QK^T (mfma(K,Q)) puts P in registers per q-col; cvt_pk+permlane32_swap
// builds PV A-fragments with ZERO P LDS traffic. K/V staged via global_load_lds
// into chunked layouts (conflict-free b128 reads), double-buffered.
__global__ __launch_bounds__(512, 4) void attn_kernel(
    const unsigned short* __restrict__ Q, const unsigned short* __restrict__ Kp,
    const unsigned short* __restrict__ Vt, const int* __restrict__ mask,
    unsigned short* __restrict__ out)
{
    // K dbuf: [2][8 dchunk][128 k][16B] @ 0,16384
    // V dbuf: [2][16 kchunk][64 d][16B] @ 32768,49152
    // after loop: Oex f32[4][32][64] @ 0 ; lsum f32[4][2][32] @ 32768
    __shared__ __align__(16) char lds[65536];

    const int tid = threadIdx.x, lane = tid & 63, wave = tid >> 6;
    const int qb = wave >> 1, kh = wave & 1;
    const int r32 = lane & 31, hi = lane >> 5;
    const int bh = blockIdx.y, bb = bh >> 2, hh = bh & 3;
    const int q0 = blockIdx.x * 128;
    const size_t baseQ = (size_t)bh * CS * CDH;   // Q,K: [S][DH]
    const size_t baseT = (size_t)bh * CDH * CS;   // Vt:  [DH][S]

    // ---- Q fragments in registers (B-operand: col=q, k-chunk = dw*16+hi*8) ----
    const int qrow = q0 + qb * 32 + r32;
    bf16x8 qf[4];
    {
        const bool live = (mask[bb * CS + qrow] != 0);
        #pragma unroll
        for (int dw = 0; dw < 4; ++dw) {
            uint4 v = {0u, 0u, 0u, 0u};
            if (live) v = *(const uint4*)(Q + baseQ + (size_t)qrow * CDH + dw * 16 + hi * 8);
            qf[dw] = *(bf16x8*)&v;
        }
    }

    // staging: 1024 16B slots each for K and V; wave w covers slots [w*64+i*512 .. +63]
#define STAGE(BUF, KT) do {                                                             \
        _Pragma("unroll")                                                               \
        for (int i = 0; i < 2; ++i) {                                                   \
            const int slot0 = i * 512 + wave * 64;                                      \
            const int slot  = slot0 + lane;                                             \
            const int kw = slot >> 7, kk2 = slot & 127;                                 \
            GLOAD_LDS16(Kp + baseQ + (size_t)((KT) + kk2) * CDH + kw * 8,               \
                        lds + (BUF) * 16384 + slot0 * 16);                              \
            const int vc = slot >> 6, vd = slot & 63;                                   \
            GLOAD_LDS16(Vt + baseT + (size_t)vd * CS + (KT) + vc * 8,                   \
                        lds + 32768 + (BUF) * 16384 + slot0 * 16);                      \
        } } while (0)

    f32x16 o0 = zero16(), o1 = zero16();
    float psum = 0.f;

    STAGE(0, 0);
    __syncthreads();

    for (int t = 0; t < CS / 128; ++t) {
        const int buf = t & 1;
        const int kt = t * 128;
        if (t + 1 < CS / 128) STAGE(buf ^ 1, kt + 128);

        const char* kbase = lds + buf * 16384;
        const char* vbase = lds + 32768 + buf * 16384;

        // ---- QK^T swapped: sT[kb] = S^T[k=kh*64+kb*32+crow][q=r32] ----
        f32x16 sT0 = zero16(), sT1 = zero16();
        __builtin_amdgcn_s_setprio(1);
        #pragma unroll
        for (int dw = 0; dw < 4; ++dw) {
            const char* cb = kbase + (dw * 2 + hi) * 2048;
            bf16x8 k0 = *(const bf16x8*)(cb + (kh * 64 + r32) * 16);
            bf16x8 k1 = *(const bf16x8*)(cb + (kh * 64 + 32 + r32) * 16);
            sT0 = mfma32(k0, qf[dw], sT0);
            sT1 = mfma32(k1, qf[dw], sT1);
        }
        __builtin_amdgcn_s_setprio(0);

        // ---- p=exp2(s); cvt_pk; permlane -> PV A-frags; PV MFMA; no LDS for P ----
#define PROCKB(SREG, KB) do {                                                           \
            float p[16];                                                                \
            _Pragma("unroll")                                                           \
            for (int r = 0; r < 16; ++r) { p[r] = fexp2((SREG)[r]); psum += p[r]; }     \
            _Pragma("unroll")                                                           \
            for (int w = 0; w < 2; ++w) {                                               \
                unsigned int a01 = packbf(p[w*8+0], p[w*8+1]);                          \
                unsigned int a23 = packbf(p[w*8+2], p[w*8+3]);                          \
                unsigned int b01 = packbf(p[w*8+4], p[w*8+5]);                          \
                unsigned int b23 = packbf(p[w*8+6], p[w*8+7]);                          \
                unsigned int ap0, ap1, ap2, ap3;                                        \
                {                                                                       \
                    i32x2 s1 = __builtin_amdgcn_permlane32_swap((int)a01, (int)b01, false, false); \
                    i32x2 s2 = __builtin_amdgcn_permlane32_swap((int)a23, (int)b23, false, false); \
                    ap0 = (unsigned int)s1.x; ap2 = (unsigned int)s1.y;                 \
                    ap1 = (unsigned int)s2.x; ap3 = (unsigned int)s2.y;                 \
                }                                                                       \
                union { unsigned int u[4]; bf16x8 v; } apv;                             \
                apv.u[0] = ap0; apv.u[1] = ap1; apv.u[2] = ap2; apv.u[3] = ap3;         \
                const char* vb2 = vbase + ((kh * 4 + (KB) * 2 + w) * 2 + hi) * 1024;    \
                bf16x8 v0 = *(const bf16x8*)(vb2 + r32 * 16);                           \
                bf16x8 v1 = *(const bf16x8*)(vb2 + (32 + r32) * 16);                    \
                o0 = mfma32(apv.v, v0, o0);                                             \
                o1 = mfma32(apv.v, v1, o1);                                             \
            } } while (0)

        PROCKB(sT0, 0);
        PROCKB(sT1, 1);
#undef PROCKB

        __syncthreads();   // staged buf^1 complete (vmcnt drain) + all reads of buf done
    }

    // ---- end reduction: cross-hi psum, cross-kh O and l via LDS ----
    float ps = psum + __shfl_xor(psum, 32, 64);     // full k-half sum for q=qb*32+r32
    float* lsum = (float*)(lds + 32768);            // [4][2][32]
    float* Oex  = (float*)lds;                      // [4][32][64]
    if (lane < 32) lsum[(qb * 2 + kh) * 32 + r32] = ps;
    if (kh == 1) {
        #pragma unroll
        for (int r = 0; r < 16; ++r) {
            const int qr = (r & 3) + 8 * (r >> 2) + 4 * hi;
            Oex[(qb * 32 + qr) * 64 + r32]      = o0[r];
            Oex[(qb * 32 + qr) * 64 + 32 + r32] = o1[r];
        }
    }
    __syncthreads();
    if (kh == 0) {
        #pragma unroll
        for (int r = 0; r < 16; ++r) {
            const int qr = (r & 3) + 8 * (r >> 2) + 4 * hi;
            const float l = lsum[(qb * 2 + 0) * 32 + qr] + lsum[(qb * 2 + 1) * 32 + qr];
            const float inv = 1.0f / l;
            const float u0 = (o0[r] + Oex[(qb * 32 + qr) * 64 + r32]) * inv;
            const float u1 = (o1[r] + Oex[(qb * 32 + qr) * 64 + 32 + r32]) * inv;
            const size_t ob = (size_t)(bb * CS + q0 + qb * 32 + qr) * CH + hh * CDH;
            out[ob + r32]      = f2b(u0);
            out[ob + 32 + r32] = f2b(u1);
        }
    }
#undef STAGE
}

// ----------------------------------------------------------------------------------
extern "C" void kernel_launch(void* const* d_in, const int* in_sizes, int n_in,
                              void* d_out, int out_size, void* d_ws, size_t ws_size,
                              hipStream_t stream)
{
    const void* hidden = d_in[0];
    const void* Wq = d_in[1];  const void* bq = d_in[2];
    const void* Wk = d_in[3];  const void* bk = d_in[4];
    const void* Wv = d_in[5];  const void* bv = d_in[6];
    const void* Wo = d_in[7];  const void* bo = d_in[8];
    const void* W1 = d_in[9];  const void* b1 = d_in[10];
    const void* W2 = d_in[11]; const void* b2 = d_in[12];
    const void* ln1w = d_in[13]; const void* ln1b = d_in[14];
    const void* ln2w = d_in[15]; const void* ln2b = d_in[16];
    const int* mask = (const int*)d_in[17];

    char* ws = (char*)d_ws;
    const size_t KB = 1u << 10, MB = 1u << 20;
    int*            flag  = (int*)ws;
    float*          bqf   = (float*)(ws + 4*KB);
    float*          bkf   = (float*)(ws + 8*KB);
    float*          bvf   = (float*)(ws + 12*KB);
    float*          bof   = (float*)(ws + 16*KB);
    float*          b1f   = (float*)(ws + 20*KB);
    float*          b2f_  = (float*)(ws + 28*KB);
    float*          ln1wf = (float*)(ws + 32*KB);
    float*          ln1bf = (float*)(ws + 36*KB);
    float*          ln2wf = (float*)(ws + 40*KB);
    float*          ln2bf = (float*)(ws + 44*KB);
    unsigned short* Wqb   = (unsigned short*)(ws + 1*MB);
    unsigned short* Wkb   = (unsigned short*)(ws + 1*MB + 256*KB);
    unsigned short* Wvb   = (unsigned short*)(ws + 1*MB + 512*KB);
    unsigned short* Wob   = (unsigned short*)(ws + 1*MB + 768*KB);
    unsigned short* W1b   = (unsigned short*)(ws + 2*MB);
    unsigned short* W2b   = (unsigned short*)(ws + 2*MB + 512*KB);
    unsigned short* hb16  = (unsigned short*)(ws + 3*MB);   // [T][H] bf16, 8MB
    unsigned short* xhat  = (unsigned short*)(ws + 11*MB);  // 8MB
    unsigned short* qb    = (unsigned short*)(ws + 19*MB);  // 8MB
    unsigned short* kb    = (unsigned short*)(ws + 27*MB);  // 8MB
    unsigned short* vtb   = (unsigned short*)(ws + 35*MB);  // 8MB (V stored transposed)
    unsigned short* attnb = xhat;                           // xhat dead after QKV
    unsigned short* hid2b = qb;                             // qb dead after attn
    unsigned short* yhat  = kb;                             // kb dead after attn
    unsigned short* h1g   = (unsigned short*)(ws + 51*MB);  // [T][1024] bf16, 32MB

    dim3 blk(256);
    detect_kernel<<<1, blk, 0, stream>>>((const unsigned short*)hidden, flag);

    CvtW cw;
    cw.src[0]=Wq;  cw.dst[0]=Wqb;  cw.n[0]=CH*CH;
    cw.src[1]=Wk;  cw.dst[1]=Wkb;  cw.n[1]=CH*CH;
    cw.src[2]=Wv;  cw.dst[2]=Wvb;  cw.n[2]=CH*CH;
    cw.src[3]=Wo;  cw.dst[3]=Wob;  cw.n[3]=CH*CH;
    cw.src[4]=W1;  cw.dst[4]=W1b;  cw.n[4]=4*CH*CH;
    cw.src[5]=W2;  cw.dst[5]=W2b;  cw.n[5]=4*CH*CH;
    cvt_wb_k<<<dim3(128, 6), blk, 0, stream>>>(flag, cw);

    CvtB cf;
    cf.src[0]=bq;    cf.dst[0]=bqf;   cf.n[0]=CH;
    cf.src[1]=bk;    cf.dst[1]=bkf;   cf.n[1]=CH;
    cf.src[2]=bv;    cf.dst[2]=bvf;   cf.n[2]=CH;
    cf.src[3]=bo;    cf.dst[3]=bof;   cf.n[3]=CH;
    cf.src[4]=b1;    cf.dst[4]=b1f;   cf.n[4]=4*CH;
    cf.src[5]=b2;    cf.dst[5]=b2f_;  cf.n[5]=CH;
    cf.src[6]=ln1w;  cf.dst[6]=ln1wf; cf.n[6]=CH;
    cf.src[7]=ln1b;  cf.dst[7]=ln1bf; cf.n[7]=CH;
    cf.src[8]=ln2w;  cf.dst[8]=ln2wf; cf.n[8]=CH;
    cf.src[9]=ln2b;  cf.dst[9]=ln2bf; cf.n[9]=CH;
    cvt_bf_k<<<dim3(1, 10), blk, 0, stream>>>(flag, cf);

    ln1_dyn_kernel<<<CT / 4, blk, 0, stream>>>(hidden, flag, ln1wf, ln1bf, xhat, hb16);
    k_qkv<<<dim3(CT / 128, CH / 128, 3), blk, 0, stream>>>(xhat, Wqb, bqf, qb,
                                                           Wkb, bkf, kb, Wvb, bvf, vtb);
    attn_kernel<<<dim3(CS / 128, CB * CNH), dim3(512), 0, stream>>>(qb, kb, vtb, mask, attnb);
    k_oproj<<<dim3(CT / 128, CH / 128), blk, 0, stream>>>(attnb, Wob, bof, hb16, hid2b);
    ln_kernel<<<CT / 4, blk, 0, stream>>>(hid2b, ln2wf, ln2bf, yhat);
    k_ffn1<<<dim3(CT / 128, (4 * CH) / 128), blk, 0, stream>>>(yhat, W1b, b1f, h1g);
    k_ffn2<<<dim3(CT / 128, CH / 128), blk, 0, stream>>>(h1g, W2b, b2f_, hid2b,
                                                         d_out, flag);
}

// Round 16
// 156.060 us; speedup vs baseline: 2.6653x; 1.0282x over previous
//
#include <hip/hip_runtime.h>
#include <hip/hip_bf16.h>
#include <cstdint>
#include <cstddef>

constexpr int CB  = 8;
constexpr int CS  = 2048;
constexpr int CH  = 256;
constexpr int CNH = 4;
constexpr int CDH = 64;
constexpr int CT  = CB * CS;   // 16384 tokens

typedef __attribute__((ext_vector_type(8)))  __bf16 bf16x8;
typedef __attribute__((ext_vector_type(4)))  float  f32x4;
typedef __attribute__((ext_vector_type(16))) float  f32x16;
typedef __attribute__((ext_vector_type(2)))  int    i32x2;

__device__ __forceinline__ float b2f(unsigned short u) {
    union { float f; unsigned int i; } v; v.i = ((unsigned int)u) << 16; return v.f;
}
__device__ __forceinline__ unsigned short f2b(float f) {
    union { float f; unsigned int i; } v; v.f = f;
    unsigned int r = v.i + 0x7FFFu + ((v.i >> 16) & 1u);
    return (unsigned short)(r >> 16);
}
__device__ __forceinline__ unsigned short f2b_fast(float f) {  // round-half-up
    union { float f; unsigned int i; } v; v.f = f;
    return (unsigned short)((v.i + 0x8000u) >> 16);
}
__device__ __forceinline__ unsigned int packbf(float a, float b) {
    return (unsigned int)f2b_fast(a) | ((unsigned int)f2b_fast(b) << 16);
}
__device__ __forceinline__ float fexp2(float x) {
#if __has_builtin(__builtin_amdgcn_exp2f)
    return __builtin_amdgcn_exp2f(x);
#else
    float r; asm("v_exp_f32 %0, %1" : "=v"(r) : "v"(x)); return r;
#endif
}
__device__ __forceinline__ f32x4 mfma16(bf16x8 a, bf16x8 b, f32x4 c) {
    return __builtin_amdgcn_mfma_f32_16x16x32_bf16(a, b, c, 0, 0, 0);
}
__device__ __forceinline__ f32x16 mfma32(bf16x8 a, bf16x8 b, f32x16 c) {
    return __builtin_amdgcn_mfma_f32_32x32x16_bf16(a, b, c, 0, 0, 0);
}
__device__ __forceinline__ f32x16 zero16() {
    f32x16 z;
    #pragma unroll
    for (int i = 0; i < 16; ++i) z[i] = 0.f;
    return z;
}

#define GLOAD_LDS16(gptr, lptr)                                                        \
    __builtin_amdgcn_global_load_lds((const __attribute__((address_space(1))) void*)(gptr), \
                                     (__attribute__((address_space(3))) void*)(lptr), 16, 0, 0)

// log2(e)/sqrt(DH): folded into Q projection so softmax uses raw exp2
#define QSCALE 0.1803368801111204f

// ---------------- dtype detect: reading f32 data as bf16 yields huge/NaN values ----
__global__ __launch_bounds__(256) void detect_kernel(
    const unsigned short* __restrict__ h, int* __restrict__ flag)
{
    __shared__ int s_bad;
    const int tid = threadIdx.x;
    if (tid == 0) s_bad = 0;
    __syncthreads();
    bool bad = false;
    for (int i = tid; i < 2048; i += 256) {
        float v = b2f(h[i]);
        if (!(fabsf(v) < 1e25f)) bad = true;   // NaN also lands here
    }
    if (bad) s_bad = 1;
    __syncthreads();
    if (tid == 0) *flag = s_bad;               // 1 => buffers are f32, 0 => bf16
}

// ---------------- converters (runtime input dtype via flag) -----------------------
struct CvtW { const void* src[6]; void* dst[6]; int n[6]; };   // -> bf16 (weights)
struct CvtB { const void* src[10]; void* dst[10]; int n[10]; };// -> f32 (biases/ln, tiny)

__global__ __launch_bounds__(256) void cvt_wb_k(const int* __restrict__ flag, CvtW a)
{
    const int seg = blockIdx.y, n = a.n[seg];
    const bool inf32 = (*flag != 0);
    const float* sf = (const float*)a.src[seg];
    const unsigned short* sb = (const unsigned short*)a.src[seg];
    unsigned short* d = (unsigned short*)a.dst[seg];
    for (int i = (blockIdx.x * 256 + threadIdx.x) * 4; i < n; i += gridDim.x * 1024) {
        ushort4 o;
        if (inf32) {
            float4 v = *(const float4*)(sf + i);
            o.x = f2b(v.x); o.y = f2b(v.y); o.z = f2b(v.z); o.w = f2b(v.w);
        } else {
            o = *(const ushort4*)(sb + i);
        }
        *(ushort4*)(d + i) = o;
    }
}

__global__ __launch_bounds__(256) void cvt_bf_k(const int* __restrict__ flag, CvtB a)
{
    const int seg = blockIdx.y, n = a.n[seg];
    const bool inf32 = (*flag != 0);
    const float* sf = (const float*)a.src[seg];
    const unsigned short* sb = (const unsigned short*)a.src[seg];
    float* d = (float*)a.dst[seg];
    const int i = threadIdx.x * 4;
    if (i < n) {
        float4 o;
        if (inf32) {
            o = *(const float4*)(sf + i);
        } else {
            ushort4 v = *(const ushort4*)(sb + i);
            o.x = b2f(v.x); o.y = b2f(v.y); o.z = b2f(v.z); o.w = b2f(v.w);
        }
        *(float4*)(d + i) = o;
    }
}

// ---------------- LN1 fused with input conversion: raw hidden -> xhat + hb16 ------
__global__ __launch_bounds__(256) void ln1_dyn_kernel(
    const void* __restrict__ x, const int* __restrict__ flag,
    const float* __restrict__ w, const float* __restrict__ b,
    unsigned short* __restrict__ xout, unsigned short* __restrict__ hcopy)
{
    const int wave = threadIdx.x >> 6, lane = threadIdx.x & 63;
    const int token = blockIdx.x * 4 + wave;
    const int c = lane * 4;
    const size_t rowo = (size_t)token * CH + c;
    float v0, v1, v2, v3;
    if (*flag != 0) {
        float4 u = *(const float4*)((const float*)x + rowo);
        v0 = u.x; v1 = u.y; v2 = u.z; v3 = u.w;
    } else {
        ushort4 u = *(const ushort4*)((const unsigned short*)x + rowo);
        v0 = b2f(u.x); v1 = b2f(u.y); v2 = b2f(u.z); v3 = b2f(u.w);
    }
    ushort4 hc;
    hc.x = f2b(v0); hc.y = f2b(v1); hc.z = f2b(v2); hc.w = f2b(v3);
    *(ushort4*)(hcopy + rowo) = hc;                 // bf16 residual copy
    float s = v0 + v1 + v2 + v3;
    float q = v0*v0 + v1*v1 + v2*v2 + v3*v3;
    #pragma unroll
    for (int m = 1; m < 64; m <<= 1) { s += __shfl_xor(s, m, 64); q += __shfl_xor(q, m, 64); }
    float mean = s * (1.0f/256.0f);
    float var  = q * (1.0f/256.0f) - mean*mean;
    float inv  = rsqrtf(var + 1e-12f);
    float4 ww = *(const float4*)(w + c);
    float4 bb = *(const float4*)(b + c);
    ushort4 o;
    o.x = f2b(ww.x * (v0-mean)*inv + bb.x);
    o.y = f2b(ww.y * (v1-mean)*inv + bb.y);
    o.z = f2b(ww.z * (v2-mean)*inv + bb.z);
    o.w = f2b(ww.w * (v3-mean)*inv + bb.w);
    *(ushort4*)(xout + rowo) = o;
}

// ---------------- LayerNorm (bf16 in), for LN2 ------------------------------------
__global__ __launch_bounds__(256) void ln_kernel(
    const unsigned short* __restrict__ x, const float* __restrict__ w,
    const float* __restrict__ b, unsigned short* __restrict__ out)
{
    const int wave = threadIdx.x >> 6, lane = threadIdx.x & 63;
    const int token = blockIdx.x * 4 + wave;
    const int c = lane * 4;
    const size_t rowo = (size_t)token * CH + c;
    ushort4 u = *(const ushort4*)(x + rowo);
    float v0 = b2f(u.x), v1 = b2f(u.y), v2 = b2f(u.z), v3 = b2f(u.w);
    float s = v0 + v1 + v2 + v3;
    float q = v0*v0 + v1*v1 + v2*v2 + v3*v3;
    #pragma unroll
    for (int m = 1; m < 64; m <<= 1) { s += __shfl_xor(s, m, 64); q += __shfl_xor(q, m, 64); }
    float mean = s * (1.0f/256.0f);
    float var  = q * (1.0f/256.0f) - mean*mean;
    float inv  = rsqrtf(var + 1e-12f);
    float4 ww = *(const float4*)(w + c);
    float4 bb = *(const float4*)(b + c);
    ushort4 o;
    o.x = f2b(ww.x * (v0-mean)*inv + bb.x);
    o.y = f2b(ww.y * (v1-mean)*inv + bb.y);
    o.z = f2b(ww.z * (v2-mean)*inv + bb.z);
    o.w = f2b(ww.w * (v3-mean)*inv + bb.w);
    *(ushort4*)(out + rowo) = o;
}

// ---------------- 128x128 bf16 MFMA GEMM, BK=128 (64 MFMA per barrier pair) -------
// A:[M][K] W:[N][K] bf16; bias f32; resid bf16. 4 waves, each 64x64 (4x4 frags).
// LDS: lA/lB [128 rows][128 k] bf16 (256B rows, 32 KB each). Quarter swizzle:
// 16B unit j of row holds global 16B quarter j^(row&7); staged via pre-swizzled
// source (16 lanes still cover one full 256B row -> coalescing preserved); reads
// apply the same XOR -> 2-way banks (free). K=256 -> only 2 iterations.
// storemode: 0=row, 1=head ([B][NH][S][DH]), 2=V^T ([B][NH][DH][S], 8B packed).
template<bool GELU, bool RESID, bool OUTDYN>
__device__ __forceinline__ void gemm_core(
    const unsigned short* __restrict__ A, const unsigned short* __restrict__ W,
    const float* __restrict__ bias, const unsigned short* __restrict__ resid,
    void* __restrict__ out, const int* __restrict__ flag,
    int K, int N, int m0, int n0, float oscale, int storemode)
{
    __shared__ __align__(16) unsigned short lA[128*128];   // 32 KB
    __shared__ __align__(16) unsigned short lB[128*128];   // 32 KB
    const int tid  = threadIdx.x;
    const int lane = tid & 63;
    const int wave = tid >> 6;
    const int wr = (wave >> 1) * 64;
    const int wc = (wave & 1) * 64;
    const int g = lane >> 4, r16 = lane & 15;

    const f32x4 zero = {0.f, 0.f, 0.f, 0.f};
    f32x4 acc[4][4];
    #pragma unroll
    for (int m = 0; m < 4; ++m)
        #pragma unroll
        for (int n = 0; n < 4; ++n) acc[m][n] = zero;

    for (int k0 = 0; k0 < K; k0 += 128) {
        #pragma unroll
        for (int i = 0; i < 8; ++i) {          // 2048 16B slots each; 8 loads/thread
            const int slot0 = i * 256 + wave * 64;     // covers 0..2047, wave-uniform
            const int slot  = slot0 + lane;
            const int row = slot >> 4;
            const int q   = (slot & 15) ^ (row & 7);   // pre-swizzled source quarter
            GLOAD_LDS16(A + (size_t)(m0 + row) * K + k0 + q * 8, (char*)lA + slot0 * 16);
            GLOAD_LDS16(W + (size_t)(n0 + row) * K + k0 + q * 8, (char*)lB + slot0 * 16);
        }
        __syncthreads();                       // staged (vmcnt drained by barrier)
        #pragma unroll
        for (int kk = 0; kk < 4; ++kk) {
            bf16x8 af[4], wf[4];
            #pragma unroll
            for (int m = 0; m < 4; ++m) {
                const int arow = wr + m*16 + r16;
                const int c = (kk*4 + g) ^ (arow & 7);
                af[m] = *(const bf16x8*)((char*)lA + arow * 256 + c * 16);
            }
            #pragma unroll
            for (int n = 0; n < 4; ++n) {
                const int brow = wc + n*16 + r16;
                const int c = (kk*4 + g) ^ (brow & 7);
                wf[n] = *(const bf16x8*)((char*)lB + brow * 256 + c * 16);
            }
            #pragma unroll
            for (int m = 0; m < 4; ++m)
                #pragma unroll
                for (int n = 0; n < 4; ++n)
                    acc[m][n] = mfma16(af[m], wf[n], acc[m][n]);
        }
        if (k0 + 128 < K) __syncthreads();     // reads done before restage
    }

    const bool of32dyn = OUTDYN ? (*flag != 0) : false;
    #pragma unroll
    for (int n = 0; n < 4; ++n) {
        int col = n0 + wc + n*16 + r16;
        float bv = bias[col];
        #pragma unroll
        for (int m = 0; m < 4; ++m) {
            int row0 = m0 + wr + m*16 + g*4;
            if (storemode == 2) {                  // V^T: 4 consecutive s -> 8B pack
                ushort4 pk;
                unsigned short* pp = (unsigned short*)&pk;
                #pragma unroll
                for (int r = 0; r < 4; ++r) pp[r] = f2b(acc[m][n][r] + bv);
                const int hh = col >> 6, d = col & 63;
                const int bb = row0 >> 11, ss = row0 & 2047;
                *(ushort4*)((unsigned short*)out +
                    (((size_t)(bb * CNH + hh)) * CDH + d) * CS + ss) = pk;
            } else {
                #pragma unroll
                for (int r = 0; r < 4; ++r) {
                    int row = row0 + r;
                    float v = (acc[m][n][r] + bv) * oscale;
                    if (GELU) {
                        float a = 0.79788456080286541f * (v + 0.044715f * v * v * v);
                        v = v * (1.0f / (1.0f + __expf(-2.0f * a)));   // 0.5v(1+tanh)
                    }
                    if (RESID) v += b2f(resid[(size_t)row * N + col]);
                    size_t oidx;
                    if (storemode == 1) {
                        int hh = col >> 6, d = col & 63;
                        int bb = row >> 11, ss = row & 2047;
                        oidx = ((((size_t)bb * CNH + hh) * CS) + ss) * CDH + d;
                    } else {
                        oidx = (size_t)row * N + col;
                    }
                    if (OUTDYN && of32dyn) ((float*)out)[oidx] = v;
                    else                   ((unsigned short*)out)[oidx] = f2b(v);
                }
            }
        }
    }
}

// grids: blockIdx.x = m (fast; disjoint per-XCD A tiles), y = n, z = projection.
__global__ __launch_bounds__(256) void k_qkv(
    const unsigned short* __restrict__ xhat,
    const unsigned short* Wq, const float* bq, unsigned short* q,
    const unsigned short* Wk, const float* bk, unsigned short* k,
    const unsigned short* Wv, const float* bv, unsigned short* v)
{
    const unsigned short* W  = blockIdx.z == 0 ? Wq : (blockIdx.z == 1 ? Wk : Wv);
    const float*          bi = blockIdx.z == 0 ? bq : (blockIdx.z == 1 ? bk : bv);
    unsigned short*       o  = blockIdx.z == 0 ? q  : (blockIdx.z == 1 ? k  : v);
    const float osc = blockIdx.z == 0 ? QSCALE : 1.0f;     // fold log2e/sqrt(DH) into Q
    const int sm = blockIdx.z == 2 ? 2 : 1;                // V stored transposed
    gemm_core<false, false, false>(xhat, W, bi, nullptr, o, nullptr,
                                   CH, CH, blockIdx.x * 128, blockIdx.y * 128, osc, sm);
}

__global__ __launch_bounds__(256) void k_oproj(
    const unsigned short* __restrict__ A, const unsigned short* __restrict__ W,
    const float* __restrict__ bias, const unsigned short* __restrict__ resid,
    unsigned short* __restrict__ out)
{
    gemm_core<false, true, false>(A, W, bias, resid, out, nullptr,
                                  CH, CH, blockIdx.x * 128, blockIdx.y * 128, 1.0f, 0);
}

__global__ __launch_bounds__(256) void k_ffn1(
    const unsigned short* __restrict__ A, const unsigned short* __restrict__ W,
    const float* __restrict__ bias, unsigned short* __restrict__ out)
{
    gemm_core<true, false, false>(A, W, bias, nullptr, out, nullptr,
                                  CH, 4*CH, blockIdx.x * 128, blockIdx.y * 128, 1.0f, 0);
}

__global__ __launch_bounds__(256) void k_ffn2(
    const unsigned short* __restrict__ A, const unsigned short* __restrict__ W,
    const float* __restrict__ bias, const unsigned short* __restrict__ resid,
    void* __restrict__ out, const int* __restrict__ flag)
{
    gemm_core<false, true, true>(A, W, bias, resid, out, flag,
                                 4*CH, CH, blockIdx.x * 128, blockIdx.y * 128, 1.0f, 0);
}

// ---------------- Flash attention, 32x32 MFMA, in-register P (round-5 proven) -----
// 512 thr / 8 waves = 4 q-blocks(32) x 2 k-halves(64). QBLK=128, KVBLK=128.
// Swapped QK^T (mfma(K,Q)) puts P in registers per q-col; cvt_pk+permlane32_swap
// builds PV A-fragments with ZERO P LDS traffic. K/V staged via global_load_lds
// into chunked layouts (conflict-free b128 reads), double-buffered.
__global__ __launch_bounds__(512, 4) void attn_kernel(
    const unsigned short* __restrict__ Q, const unsigned short* __restrict__ Kp,
    const unsigned short* __restrict__ Vt, const int* __restrict__ mask,
    unsigned short* __restrict__ out)
{
    // K dbuf: [2][8 dchunk][128 k][16B] @ 0,16384
    // V dbuf: [2][16 kchunk][64 d][16B] @ 32768,49152
    // after loop: Oex f32[4][32][64] @ 0 ; lsum f32[4][2][32] @ 32768
    __shared__ __align__(16) char lds[65536];

    const int tid = threadIdx.x, lane = tid & 63, wave = tid >> 6;
    const int qb = wave >> 1, kh = wave & 1;
    const int r32 = lane & 31, hi = lane >> 5;
    const int bh = blockIdx.y, bb = bh >> 2, hh = bh & 3;
    const int q0 = blockIdx.x * 128;
    const size_t baseQ = (size_t)bh * CS * CDH;   // Q,K: [S][DH]
    const size_t baseT = (size_t)bh * CDH * CS;   // Vt:  [DH][S]

    // ---- Q fragments in registers (B-operand: col=q, k-chunk = dw*16+hi*8) ----
    const int qrow = q0 + qb * 32 + r32;
    bf16x8 qf[4];
    {
        const bool live = (mask[bb * CS + qrow] != 0);
        #pragma unroll
        for (int dw = 0; dw < 4; ++dw) {
            uint4 v = {0u, 0u, 0u, 0u};
            if (live) v = *(const uint4*)(Q + baseQ + (size_t)qrow * CDH + dw * 16 + hi * 8);
            qf[dw] = *(bf16x8*)&v;
        }
    }

    // staging: 1024 16B slots each for K and V; wave w covers slots [w*64+i*512 .. +63]
#define STAGE(BUF, KT) do {                                                             \
        _Pragma("unroll")                                                               \
        for (int i = 0; i < 2; ++i) {                                                   \
            const int slot0 = i * 512 + wave * 64;                                      \
            const int slot  = slot0 + lane;                                             \
            const int kw = slot >> 7, kk2 = slot & 127;                                 \
            GLOAD_LDS16(Kp + baseQ + (size_t)((KT) + kk2) * CDH + kw * 8,               \
                        lds + (BUF) * 16384 + slot0 * 16);                              \
            const int vc = slot >> 6, vd = slot & 63;                                   \
            GLOAD_LDS16(Vt + baseT + (size_t)vd * CS + (KT) + vc * 8,                   \
                        lds + 32768 + (BUF) * 16384 + slot0 * 16);                      \
        } } while (0)

    f32x16 o0 = zero16(), o1 = zero16();
    float psum = 0.f;

    STAGE(0, 0);
    __syncthreads();

    for (int t = 0; t < CS / 128; ++t) {
        const int buf = t & 1;
        const int kt = t * 128;
        if (t + 1 < CS / 128) STAGE(buf ^ 1, kt + 128);

        const char* kbase = lds + buf * 16384;
        const char* vbase = lds + 32768 + buf * 16384;

        // ---- QK^T swapped: sT[kb] = S^T[k=kh*64+kb*32+crow][q=r32] ----
        f32x16 sT0 = zero16(), sT1 = zero16();
        __builtin_amdgcn_s_setprio(1);
        #pragma unroll
        for (int dw = 0; dw < 4; ++dw) {
            const char* cb = kbase + (dw * 2 + hi) * 2048;
            bf16x8 k0 = *(const bf16x8*)(cb + (kh * 64 + r32) * 16);
            bf16x8 k1 = *(const bf16x8*)(cb + (kh * 64 + 32 + r32) * 16);
            sT0 = mfma32(k0, qf[dw], sT0);
            sT1 = mfma32(k1, qf[dw], sT1);
        }
        __builtin_amdgcn_s_setprio(0);

        // ---- p=exp2(s); cvt_pk; permlane -> PV A-frags; PV MFMA; no LDS for P ----
#define PROCKB(SREG, KB) do {                                                           \
            float p[16];                                                                \
            _Pragma("unroll")                                                           \
            for (int r = 0; r < 16; ++r) { p[r] = fexp2((SREG)[r]); psum += p[r]; }     \
            _Pragma("unroll")                                                           \
            for (int w = 0; w < 2; ++w) {                                               \
                unsigned int a01 = packbf(p[w*8+0], p[w*8+1]);                          \
                unsigned int a23 = packbf(p[w*8+2], p[w*8+3]);                          \
                unsigned int b01 = packbf(p[w*8+4], p[w*8+5]);                          \
                unsigned int b23 = packbf(p[w*8+6], p[w*8+7]);                          \
                unsigned int ap0, ap1, ap2, ap3;                                        \
                {                                                                       \
                    i32x2 s1 = __builtin_amdgcn_permlane32_swap((int)a01, (int)b01, false, false); \
                    i32x2 s2 = __builtin_amdgcn_permlane32_swap((int)a23, (int)b23, false, false); \
                    ap0 = (unsigned int)s1.x; ap2 = (unsigned int)s1.y;                 \
                    ap1 = (unsigned int)s2.x; ap3 = (unsigned int)s2.y;                 \
                }                                                                       \
                union { unsigned int u[4]; bf16x8 v; } apv;                             \
                apv.u[0] = ap0; apv.u[1] = ap1; apv.u[2] = ap2; apv.u[3] = ap3;         \
                const char* vb2 = vbase + ((kh * 4 + (KB) * 2 + w) * 2 + hi) * 1024;    \
                bf16x8 v0 = *(const bf16x8*)(vb2 + r32 * 16);                           \
                bf16x8 v1 = *(const bf16x8*)(vb2 + (32 + r32) * 16);                    \
                o0 = mfma32(apv.v, v0, o0);                                             \
                o1 = mfma32(apv.v, v1, o1);                                             \
            } } while (0)

        PROCKB(sT0, 0);
        PROCKB(sT1, 1);
#undef PROCKB

        __syncthreads();   // staged buf^1 complete (vmcnt drain) + all reads of buf done
    }

    // ---- end reduction: cross-hi psum, cross-kh O and l via LDS ----
    float ps = psum + __shfl_xor(psum, 32, 64);     // full k-half sum for q=qb*32+r32
    float* lsum = (float*)(lds + 32768);            // [4][2][32]
    float* Oex  = (float*)lds;                      // [4][32][64]
    if (lane < 32) lsum[(qb * 2 + kh) * 32 + r32] = ps;
    if (kh == 1) {
        #pragma unroll
        for (int r = 0; r < 16; ++r) {
            const int qr = (r & 3) + 8 * (r >> 2) + 4 * hi;
            Oex[(qb * 32 + qr) * 64 + r32]      = o0[r];
            Oex[(qb * 32 + qr) * 64 + 32 + r32] = o1[r];
        }
    }
    __syncthreads();
    if (kh == 0) {
        #pragma unroll
        for (int r = 0; r < 16; ++r) {
            const int qr = (r & 3) + 8 * (r >> 2) + 4 * hi;
            const float l = lsum[(qb * 2 + 0) * 32 + qr] + lsum[(qb * 2 + 1) * 32 + qr];
            const float inv = 1.0f / l;
            const float u0 = (o0[r] + Oex[(qb * 32 + qr) * 64 + r32]) * inv;
            const float u1 = (o1[r] + Oex[(qb * 32 + qr) * 64 + 32 + r32]) * inv;
            const size_t ob = (size_t)(bb * CS + q0 + qb * 32 + qr) * CH + hh * CDH;
            out[ob + r32]      = f2b(u0);
            out[ob + 32 + r32] = f2b(u1);
        }
    }
#undef STAGE
}

// ----------------------------------------------------------------------------------
extern "C" void kernel_launch(void* const* d_in, const int* in_sizes, int n_in,
                              void* d_out, int out_size, void* d_ws, size_t ws_size,
                              hipStream_t stream)
{
    const void* hidden = d_in[0];
    const void* Wq = d_in[1];  const void* bq = d_in[2];
    const void* Wk = d_in[3];  const void* bk = d_in[4];
    const void* Wv = d_in[5];  const void* bv = d_in[6];
    const void* Wo = d_in[7];  const void* bo = d_in[8];
    const void* W1 = d_in[9];  const void* b1 = d_in[10];
    const void* W2 = d_in[11]; const void* b2 = d_in[12];
    const void* ln1w = d_in[13]; const void* ln1b = d_in[14];
    const void* ln2w = d_in[15]; const void* ln2b = d_in[16];
    const int* mask = (const int*)d_in[17];

    char* ws = (char*)d_ws;
    const size_t KB = 1u << 10, MB = 1u << 20;
    int*            flag  = (int*)ws;
    float*          bqf   = (float*)(ws + 4*KB);
    float*          bkf   = (float*)(ws + 8*KB);
    float*          bvf   = (float*)(ws + 12*KB);
    float*          bof   = (float*)(ws + 16*KB);
    float*          b1f   = (float*)(ws + 20*KB);
    float*          b2f_  = (float*)(ws + 28*KB);
    float*          ln1wf = (float*)(ws + 32*KB);
    float*          ln1bf = (float*)(ws + 36*KB);
    float*          ln2wf = (float*)(ws + 40*KB);
    float*          ln2bf = (float*)(ws + 44*KB);
    unsigned short* Wqb   = (unsigned short*)(ws + 1*MB);
    unsigned short* Wkb   = (unsigned short*)(ws + 1*MB + 256*KB);
    unsigned short* Wvb   = (unsigned short*)(ws + 1*MB + 512*KB);
    unsigned short* Wob   = (unsigned short*)(ws + 1*MB + 768*KB);
    unsigned short* W1b   = (unsigned short*)(ws + 2*MB);
    unsigned short* W2b   = (unsigned short*)(ws + 2*MB + 512*KB);
    unsigned short* hb16  = (unsigned short*)(ws + 3*MB);   // [T][H] bf16, 8MB
    unsigned short* xhat  = (unsigned short*)(ws + 11*MB);  // 8MB
    unsigned short* qb    = (unsigned short*)(ws + 19*MB);  // 8MB
    unsigned short* kb    = (unsigned short*)(ws + 27*MB);  // 8MB
    unsigned short* vtb   = (unsigned short*)(ws + 35*MB);  // 8MB (V stored transposed)
    unsigned short* attnb = xhat;                           // xhat dead after QKV
    unsigned short* hid2b = qb;                             // qb dead after attn
    unsigned short* yhat  = kb;                             // kb dead after attn
    unsigned short* h1g   = (unsigned short*)(ws + 51*MB);  // [T][1024] bf16, 32MB

    dim3 blk(256);
    detect_kernel<<<1, blk, 0, stream>>>((const unsigned short*)hidden, flag);

    CvtW cw;
    cw.src[0]=Wq;  cw.dst[0]=Wqb;  cw.n[0]=CH*CH;
    cw.src[1]=Wk;  cw.dst[1]=Wkb;  cw.n[1]=CH*CH;
    cw.src[2]=Wv;  cw.dst[2]=Wvb;  cw.n[2]=CH*CH;
    cw.src[3]=Wo;  cw.dst[3]=Wob;  cw.n[3]=CH*CH;
    cw.src[4]=W1;  cw.dst[4]=W1b;  cw.n[4]=4*CH*CH;
    cw.src[5]=W2;  cw.dst[5]=W2b;  cw.n[5]=4*CH*CH;
    cvt_wb_k<<<dim3(128, 6), blk, 0, stream>>>(flag, cw);

    CvtB cf;
    cf.src[0]=bq;    cf.dst[0]=bqf;   cf.n[0]=CH;
    cf.src[1]=bk;    cf.dst[1]=bkf;   cf.n[1]=CH;
    cf.src[2]=bv;    cf.dst[2]=bvf;   cf.n[2]=CH;
    cf.src[3]=bo;    cf.dst[3]=bof;   cf.n[3]=CH;
    cf.src[4]=b1;    cf.dst[4]=b1f;   cf.n[4]=4*CH;
    cf.src[5]=b2;    cf.dst[5]=b2f_;  cf.n[5]=CH;
    cf.src[6]=ln1w;  cf.dst[6]=ln1wf; cf.n[6]=CH;
    cf.src[7]=ln1b;  cf.dst[7]=ln1bf; cf.n[7]=CH;
    cf.src[8]=ln2w;  cf.dst[8]=ln2wf; cf.n[8]=CH;
    cf.src[9]=ln2b;  cf.dst[9]=ln2bf; cf.n[9]=CH;
    cvt_bf_k<<<dim3(1, 10), blk, 0, stream>>>(flag, cf);

    ln1_dyn_kernel<<<CT / 4, blk, 0, stream>>>(hidden, flag, ln1wf, ln1bf, xhat, hb16);
    k_qkv<<<dim3(CT / 128, CH / 128, 3), blk, 0, stream>>>(xhat, Wqb, bqf, qb,
                                                           Wkb, bkf, kb, Wvb, bvf, vtb);
    attn_kernel<<<dim3(CS / 128, CB * CNH), dim3(512), 0, stream>>>(qb, kb, vtb, mask, attnb);
    k_oproj<<<dim3(CT / 128, CH / 128), blk, 0, stream>>>(attnb, Wob, bof, hb16, hid2b);
    ln_kernel<<<CT / 4, blk, 0, stream>>>(hid2b, ln2wf, ln2bf, yhat);
    k_ffn1<<<dim3(CT / 128, (4 * CH) / 128), blk, 0, stream>>>(yhat, W1b, b1f, h1g);
    k_ffn2<<<dim3(CT / 128, CH / 128), blk, 0, stream>>>(h1g, W2b, b2f_, hid2b,
                                                         d_out, flag);
}